// Round 6
// baseline (24368.785 us; speedup 1.0000x reference)
//
#include <hip/hip_runtime.h>
#include <hip/hip_bf16.h>
#include <math.h>

#define NEG_SLOPE 0.2f
#define BM 64
#define BN 64
#define BK 16

typedef __hip_bfloat16 bf16;

__device__ __forceinline__ float ldf(const float* p) { return *p; }
__device__ __forceinline__ float ldf(const bf16* p) { return __bfloat162float(*p); }
__device__ __forceinline__ void stf(float* p, float v) { *p = v; }
__device__ __forceinline__ void stf(bf16* p, float v) { *p = __float2bfloat16(v); }

// edge_index accessor: flat element j of the [2,E] array, robust to int32 vs int64 storage.
__device__ __forceinline__ int eidx(const int* __restrict__ ei, int f64, long long j) {
  return f64 ? ei[2 * j] : ei[(size_t)j];
}

// ---------------- dtype detect + CSR build ----------------

__global__ void init_counts_kernel(int* counts, int* fill, int N, int* flag) {
  int i = blockIdx.x * blockDim.x + threadIdx.x;
  if (i < N) { counts[i] = 1; fill[i] = 0; }  // 1 = self-loop
  if (i == 0) *flag = 1;                      // assume int64 until disproven
}

// scan odd int32 words of the first 8E bytes (valid for both widths); nonzero => int32
__global__ void detect_kernel(const int* __restrict__ ei, int E, int* flag) {
  int i = blockIdx.x * blockDim.x + threadIdx.x;
  if (i < E && ei[2 * i + 1] != 0) atomicAnd(flag, 0);
}

__global__ void count_kernel(const int* __restrict__ ei, int E,
                             const int* __restrict__ flag, int* __restrict__ counts) {
  int i = blockIdx.x * blockDim.x + threadIdx.x;
  if (i < E) {
    int d = eidx(ei, *flag, (long long)E + i);
    atomicAdd(&counts[d], 1);
  }
}

__global__ void scan_kernel(const int* __restrict__ counts, int* __restrict__ indptr, int N) {
  __shared__ int sums[256];
  __shared__ int offs[256];
  int t = threadIdx.x;
  int chunk = (N + 255) / 256;
  int lo = t * chunk;
  int hi = lo + chunk; if (hi > N) hi = N;
  int s = 0;
  for (int i = lo; i < hi; ++i) s += counts[i];
  sums[t] = s;
  __syncthreads();
  if (t == 0) {
    int acc = 0;
    for (int i = 0; i < 256; ++i) { offs[i] = acc; acc += sums[i]; }
    indptr[N] = acc;
  }
  __syncthreads();
  int acc = offs[t];
  for (int i = lo; i < hi; ++i) { indptr[i] = acc; acc += counts[i]; }
}

__global__ void fill_kernel(const int* __restrict__ ei, int E, int N,
                            const int* __restrict__ flag,
                            const int* __restrict__ indptr,
                            int* __restrict__ fill, int* __restrict__ csr_src,
                            int* __restrict__ csr_dst) {
  int i = blockIdx.x * blockDim.x + threadIdx.x;
  int total = E + N;
  if (i >= total) return;
  int s, d;
  if (i < E) { int f = *flag; s = eidx(ei, f, i); d = eidx(ei, f, (long long)E + i); }
  else       { s = i - E;  d = s; }
  int p = indptr[d] + atomicAdd(&fill[d], 1);
  csr_src[p] = s;
  csr_dst[p] = d;
}

__global__ void copy_kernel(const float* __restrict__ a, float* __restrict__ b, int n) {
  int i = blockIdx.x * blockDim.x + threadIdx.x;
  if (i < n) b[i] = a[i];
}

// ---------------- GEMM (chunk-aware, optional dual B, optional accumulate) ----------------
// C[:,0:Fc] (+)= A[:,0:K] @ W ; A:[M x K] stride lda (type TA), W fp32 stride ldw, C type TC.

template <typename TA, typename TC, bool DUAL, bool ACCUM>
__global__ __launch_bounds__(256)
void gemm_kernel(const TA* __restrict__ A, int lda, int M, int K,
                 const float* __restrict__ Wl, const float* __restrict__ Wr,
                 int ldw, int Fc,
                 TC* __restrict__ Cl, TC* __restrict__ Cr, int ldc) {
  __shared__ float As[BK][BM + 4];
  __shared__ float Bls[BK][BN];
  __shared__ float Brs[BK][BN];
  int tid = threadIdx.x;
  int tx = tid & 15, ty = tid >> 4;
  int bn = blockIdx.x * BN, bm = blockIdx.y * BM;
  float accl[4][4] = {};
  float accr[4][4] = {};
  for (int k0 = 0; k0 < K; k0 += BK) {
#pragma unroll
    for (int i = 0; i < 4; ++i) {
      int idx = tid + i * 256;
      int r = idx >> 4, c = idx & 15;
      int gr = bm + r, gc = k0 + c;
      As[c][r] = (gr < M && gc < K) ? ldf(&A[(size_t)gr * lda + gc]) : 0.f;
    }
#pragma unroll
    for (int i = 0; i < 4; ++i) {
      int idx = tid + i * 256;
      int c = idx >> 6, n = idx & 63;
      int gc = k0 + c, gn = bn + n;
      bool ok = (gc < K && gn < Fc);
      size_t w = (size_t)gc * ldw + gn;
      Bls[c][n] = ok ? Wl[w] : 0.f;
      if (DUAL) Brs[c][n] = ok ? Wr[w] : 0.f;
    }
    __syncthreads();
#pragma unroll
    for (int kk = 0; kk < BK; ++kk) {
      float4 a = *(const float4*)&As[kk][ty * 4];
      float4 bl = *(const float4*)&Bls[kk][tx * 4];
      float av[4] = {a.x, a.y, a.z, a.w};
      float blv[4] = {bl.x, bl.y, bl.z, bl.w};
      float brv[4] = {0.f, 0.f, 0.f, 0.f};
      if (DUAL) {
        float4 br = *(const float4*)&Brs[kk][tx * 4];
        brv[0] = br.x; brv[1] = br.y; brv[2] = br.z; brv[3] = br.w;
      }
#pragma unroll
      for (int i = 0; i < 4; ++i)
#pragma unroll
        for (int j = 0; j < 4; ++j) {
          accl[i][j] += av[i] * blv[j];
          if (DUAL) accr[i][j] += av[i] * brv[j];
        }
    }
    __syncthreads();
  }
#pragma unroll
  for (int i = 0; i < 4; ++i) {
    int gr = bm + ty * 4 + i;
    if (gr >= M) continue;
#pragma unroll
    for (int j = 0; j < 4; ++j) {
      int gn = bn + tx * 4 + j;
      if (gn >= Fc) continue;
      size_t o = (size_t)gr * ldc + gn;
      float vl = accl[i][j];
      if (ACCUM) vl += ldf(&Cl[o]);
      stf(&Cl[o], vl);
      if (DUAL) {
        float vr = accr[i][j];
        if (ACCUM) vr += ldf(&Cr[o]);
        stf(&Cr[o], vr);
      }
    }
  }
}

template <typename TA, typename TC>
static void launch_gemm(const TA* A, int lda, int M, int K,
                        const float* Wl, const float* Wr, int ldw, int Fc,
                        TC* Cl, TC* Cr, int ldc, bool accum, hipStream_t st) {
  dim3 grid((Fc + BN - 1) / BN, (M + BM - 1) / BM);
  if (Wr) {
    if (accum) gemm_kernel<TA, TC, true, true><<<grid, 256, 0, st>>>(A, lda, M, K, Wl, Wr, ldw, Fc, Cl, Cr, ldc);
    else       gemm_kernel<TA, TC, true, false><<<grid, 256, 0, st>>>(A, lda, M, K, Wl, Wr, ldw, Fc, Cl, Cr, ldc);
  } else {
    if (accum) gemm_kernel<TA, TC, false, true><<<grid, 256, 0, st>>>(A, lda, M, K, Wl, Wl, ldw, Fc, Cl, Cl, ldc);
    else       gemm_kernel<TA, TC, false, false><<<grid, 256, 0, st>>>(A, lda, M, K, Wl, Wl, ldw, Fc, Cl, Cl, ldc);
  }
}

// ---------------- edge scores (chunk-accumulating) ----------------

template <typename TS, bool ACCUM>
__global__ void edge_e_kernel(const TS* __restrict__ xl, const TS* __restrict__ xr, int ldx,
                              const int* __restrict__ csr_src, const int* __restrict__ csr_dst,
                              const float* __restrict__ att, float* __restrict__ ev,
                              int Etot, int Fc) {
  int gid = blockIdx.x * blockDim.x + threadIdx.x;
  int edge = gid >> 6;
  int lane = threadIdx.x & 63;
  if (edge >= Etot) return;
  int s = csr_src[edge], d = csr_dst[edge];
  const TS* pl = xl + (size_t)s * ldx;
  const TS* pr = xr + (size_t)d * ldx;
  float acc = 0.f;
  for (int f = lane; f < Fc; f += 64) {
    float h = ldf(&pl[f]) + ldf(&pr[f]);
    h = h > 0.f ? h : NEG_SLOPE * h;
    acc += h * att[f];
  }
#pragma unroll
  for (int off = 32; off > 0; off >>= 1) acc += __shfl_down(acc, off);
  if (lane == 0) {
    if (ACCUM) ev[edge] += acc;
    else ev[edge] = acc;
  }
}

template <typename TS>
static void launch_edge(const TS* xl, const TS* xr, int ldx, const int* cs, const int* cd,
                        const float* att, float* ev, int Etot, int Fc, bool accum,
                        hipStream_t st) {
  int blocks = (int)(((long long)Etot * 64 + 255) / 256);
  if (accum) edge_e_kernel<TS, true><<<blocks, 256, 0, st>>>(xl, xr, ldx, cs, cd, att, ev, Etot, Fc);
  else       edge_e_kernel<TS, false><<<blocks, 256, 0, st>>>(xl, xr, ldx, cs, cd, att, ev, Etot, Fc);
}

// ---------------- segment softmax (in-place e -> alpha) ----------------

__global__ void softmax_kernel(float* __restrict__ ev, const int* __restrict__ indptr, int N) {
  int i = blockIdx.x * blockDim.x + threadIdx.x;
  if (i >= N) return;
  int lo = indptr[i], hi = indptr[i + 1];
  float m = -1e30f;
  for (int j = lo; j < hi; ++j) m = fmaxf(m, ev[j]);
  float s = 0.f;
  for (int j = lo; j < hi; ++j) { float x = expf(ev[j] - m); ev[j] = x; s += x; }
  float inv = 1.f / s;
  for (int j = lo; j < hi; ++j) ev[j] *= inv;
}

// ---------------- aggregation over a feature chunk ----------------

template <int NC, typename TS, typename TD>
__global__ void aggregate_kernel(const TS* __restrict__ xl, int ldx,
                                 const float* __restrict__ alpha,
                                 const int* __restrict__ csr_src, const int* __restrict__ indptr,
                                 const float* __restrict__ bias,
                                 TD* __restrict__ out, int ldout, int N, int relu) {
  int gid = blockIdx.x * blockDim.x + threadIdx.x;
  int node = gid >> 6;
  int lane = threadIdx.x & 63;
  if (node >= N) return;
  float acc[NC];
#pragma unroll
  for (int c = 0; c < NC; ++c) acc[c] = bias[lane + c * 64];
  int lo = indptr[node], hi = indptr[node + 1];
  for (int j = lo; j < hi; ++j) {
    float a = alpha[j];
    const TS* row = xl + (size_t)csr_src[j] * ldx;
#pragma unroll
    for (int c = 0; c < NC; ++c) acc[c] += a * ldf(&row[lane + c * 64]);
  }
#pragma unroll
  for (int c = 0; c < NC; ++c) {
    float v = acc[c];
    if (relu) v = fmaxf(v, 0.f);
    stf(&out[(size_t)node * ldout + lane + c * 64], v);
  }
}

template <typename TS, typename TD>
static void launch_agg(const TS* xl, int ldx, const float* alpha, const int* cs, const int* ip,
                       const float* bias, TD* out, int ldout, int N, int Fc, int relu,
                       hipStream_t st) {
  int blocks = (int)(((long long)N * 64 + 255) / 256);
  if (Fc == 256) aggregate_kernel<4, TS, TD><<<blocks, 256, 0, st>>>(xl, ldx, alpha, cs, ip, bias, out, ldout, N, relu);
  else           aggregate_kernel<2, TS, TD><<<blocks, 256, 0, st>>>(xl, ldx, alpha, cs, ip, bias, out, ldout, N, relu);
}

__global__ void aggregate3_kernel(const float* __restrict__ xl, const float* __restrict__ alpha,
                                  const int* __restrict__ csr_src, const int* __restrict__ indptr,
                                  const float* __restrict__ bias, float* __restrict__ out, int N) {
  int i = blockIdx.x * blockDim.x + threadIdx.x;
  if (i >= N) return;
  float a0 = bias[0], a1 = bias[1], a2 = bias[2];
  int lo = indptr[i], hi = indptr[i + 1];
  for (int j = lo; j < hi; ++j) {
    float a = alpha[j];
    const float* row = xl + (size_t)csr_src[j] * 3;
    a0 += a * row[0];
    a1 += a * row[1];
    a2 += a * row[2];
  }
  out[(size_t)i * 3 + 0] = a0;
  out[(size_t)i * 3 + 1] = a1;
  out[(size_t)i * 3 + 2] = a2;
}

// ---------------- launch ----------------

extern "C" void kernel_launch(void* const* d_in, const int* in_sizes, int n_in,
                              void* d_out, int out_size, void* d_ws, size_t ws_size,
                              hipStream_t stream) {
  // fp32 inputs (per reference); fp32 output. edge_index int width detected on device.
  const float* x = (const float*)d_in[0];
  const int* ei = (const int*)d_in[1];
  const int N = in_sizes[0] / 39;
  const int E = in_sizes[1] / 2;
  const int Etot = E + N;
  (void)n_in; (void)out_size;

  const float* Wl[5]; const float* Wr[5]; const float* att[5]; const float* bb[5];
  for (int l = 0; l < 5; ++l) {
    Wl[l]  = (const float*)d_in[2 + 4 * l];
    Wr[l]  = (const float*)d_in[3 + 4 * l];
    att[l] = (const float*)d_in[4 + 4 * l];
    bb[l]  = (const float*)d_in[5 + 4 * l];
  }

  char* ws = (char*)d_ws;
  size_t off = 0;
  auto alloc = [&](size_t b) -> char* {
    char* p = ws + off;
    off += (b + 255) & ~(size_t)255;
    return p;
  };
  int* counts  = (int*)alloc((size_t)N * 4);
  int* fillc   = (int*)alloc((size_t)N * 4);
  int* flag    = (int*)alloc(256);
  int* indptr  = (int*)alloc(((size_t)N + 1) * 4);
  int* csr_s   = (int*)alloc((size_t)Etot * 4);
  int* csr_d   = (int*)alloc((size_t)Etot * 4);
  float* ev    = (float*)alloc((size_t)Etot * 4);
  float* alpha1 = (float*)alloc((size_t)Etot * 4);
  char* R0 = alloc((size_t)N * 256);  // xl1c / XR3 low / out3 low
  char* R1 = alloc((size_t)N * 256);  // xr1c,out1c / XR3 high / out3 high
  char* R2 = alloc((size_t)N * 512);  // waccL fp32 / XL3 / XL4+XR4
  char* R3 = alloc((size_t)N * 512);  // waccR fp32 / out2 low / XL5,XR5
  char* R4 = alloc((size_t)N * 512);  // out2 high
  if (off > ws_size) return;  // workspace too small: clean no-op (distinct signature)

  const int tb = 256;
  init_counts_kernel<<<(N + tb - 1) / tb, tb, 0, stream>>>(counts, fillc, N, flag);
  detect_kernel<<<(E + tb - 1) / tb, tb, 0, stream>>>(ei, E, flag);
  count_kernel<<<(E + tb - 1) / tb, tb, 0, stream>>>(ei, E, flag, counts);
  scan_kernel<<<1, 256, 0, stream>>>(counts, indptr, N);
  fill_kernel<<<(Etot + tb - 1) / tb, tb, 0, stream>>>(ei, E, N, flag, indptr,
                                                       fillc, csr_s, csr_d);

  bf16* xl1c = (bf16*)R0;
  bf16* t1   = (bf16*)R1;
  float* waccL = (float*)R2;
  float* waccR = (float*)R3;
  bf16* out2 = (bf16*)R3;  // spans R3+R4 : [N,512] bf16

  // ---- Layer 1 (39 -> 1024): produce alpha1 only; out1 stays virtual ----
  for (int kc = 0; kc < 8; ++kc) {
    launch_gemm<float, bf16>(x, 39, N, 39, Wl[0] + kc * 128, Wr[0] + kc * 128, 1024, 128,
                             xl1c, t1, 128, false, stream);
    launch_edge<bf16>(xl1c, t1, 128, csr_s, csr_d, att[0] + kc * 128, ev, Etot, 128, kc > 0, stream);
  }
  softmax_kernel<<<(N + tb - 1) / tb, tb, 0, stream>>>(ev, indptr, N);
  copy_kernel<<<(Etot + tb - 1) / tb, tb, 0, stream>>>(ev, alpha1, Etot);

  auto mat_out1 = [&](int kc) {
    launch_gemm<float, bf16>(x, 39, N, 39, Wl[0] + kc * 128, nullptr, 1024, 128,
                             xl1c, (bf16*)nullptr, 128, false, stream);
    launch_agg<bf16, bf16>(xl1c, 128, alpha1, csr_s, indptr, bb[0] + kc * 128,
                           t1, 128, N, 128, 1, stream);
  };

  // ---- Layer 2 (1024 -> 512), input virtual out1 ----
  for (int fc = 0; fc < 4; ++fc) {
    for (int kc = 0; kc < 8; ++kc) {
      mat_out1(kc);
      const float* wl = Wl[1] + (size_t)kc * 128 * 512 + fc * 128;
      const float* wr = Wr[1] + (size_t)kc * 128 * 512 + fc * 128;
      launch_gemm<bf16, float>(t1, 128, N, 128, wl, wr, 512, 128, waccL, waccR, 128, kc > 0, stream);
    }
    launch_edge<float>(waccL, waccR, 128, csr_s, csr_d, att[1] + fc * 128, ev, Etot, 128, fc > 0, stream);
  }
  softmax_kernel<<<(N + tb - 1) / tb, tb, 0, stream>>>(ev, indptr, N);
  for (int i = 0; i < 4; ++i) {
    int fc = (i == 0) ? 3 : (i - 1);   // fc=3 first: waccL still holds its XL chunk
    if (i > 0) {
      for (int kc = 0; kc < 8; ++kc) {
        mat_out1(kc);
        const float* wl = Wl[1] + (size_t)kc * 128 * 512 + fc * 128;
        launch_gemm<bf16, float>(t1, 128, N, 128, wl, nullptr, 512, 128,
                                 waccL, (float*)nullptr, 128, kc > 0, stream);
      }
    }
    launch_agg<float, bf16>(waccL, 128, ev, csr_s, indptr, bb[1] + fc * 128,
                            out2 + fc * 128, 512, N, 128, 1, stream);
  }

  // ---- Layer 3 (512 -> 256) ----
  bf16* XL3 = (bf16*)R2;
  bf16* XR3 = (bf16*)R0;  // spans R0+R1
  launch_gemm<bf16, bf16>(out2, 512, N, 512, Wl[2], Wr[2], 256, 256, XL3, XR3, 256, false, stream);
  launch_edge<bf16>(XL3, XR3, 256, csr_s, csr_d, att[2], ev, Etot, 256, false, stream);
  softmax_kernel<<<(N + tb - 1) / tb, tb, 0, stream>>>(ev, indptr, N);
  bf16* out3 = XR3;
  launch_agg<bf16, bf16>(XL3, 256, ev, csr_s, indptr, bb[2], out3, 256, N, 256, 1, stream);

  // ---- Layer 4 (256 -> 128) -> d_out[0 : N*128] fp32 ----
  bf16* XL4 = (bf16*)R2;
  bf16* XR4 = (bf16*)(R2 + (size_t)N * 256);
  launch_gemm<bf16, bf16>(out3, 256, N, 256, Wl[3], Wr[3], 128, 128, XL4, XR4, 128, false, stream);
  launch_edge<bf16>(XL4, XR4, 128, csr_s, csr_d, att[3], ev, Etot, 128, false, stream);
  softmax_kernel<<<(N + tb - 1) / tb, tb, 0, stream>>>(ev, indptr, N);
  float* out4 = (float*)d_out;
  launch_agg<bf16, float>(XL4, 128, ev, csr_s, indptr, bb[3], out4, 128, N, 128, 1, stream);

  // ---- Layer 5 (128 -> 3) -> coords at d_out[N*128 :] fp32 ----
  float* XL5 = (float*)R3;
  float* XR5 = (float*)(R3 + (((size_t)N * 12 + 255) & ~(size_t)255));
  launch_gemm<float, float>(out4, 128, N, 128, Wl[4], Wr[4], 3, 3, XL5, XR5, 3, false, stream);
  launch_edge<float>(XL5, XR5, 3, csr_s, csr_d, att[4], ev, Etot, 3, false, stream);
  softmax_kernel<<<(N + tb - 1) / tb, tb, 0, stream>>>(ev, indptr, N);
  aggregate3_kernel<<<(N + tb - 1) / tb, tb, 0, stream>>>(XL5, ev, csr_s, indptr, bb[4],
                                                          (float*)d_out + (size_t)N * 128, N);
}

// Round 7
// 17282.964 us; speedup vs baseline: 1.4100x; 1.4100x over previous
//
#include <hip/hip_runtime.h>
#include <hip/hip_bf16.h>
#include <math.h>

#define NEG_SLOPE 0.2f
#define BM 64
#define BN 64
#define BK 16

typedef __hip_bfloat16 bf16;

__device__ __forceinline__ float ldf(const float* p) { return *p; }
__device__ __forceinline__ float ldf(const bf16* p) { return __bfloat162float(*p); }
__device__ __forceinline__ void stf(float* p, float v) { *p = v; }
__device__ __forceinline__ void stf(bf16* p, float v) { *p = __float2bfloat16(v); }

// edge_index accessor: flat element j of the [2,E] array, robust to int32 vs int64 storage.
__device__ __forceinline__ int eidx(const int* __restrict__ ei, int f64, long long j) {
  return f64 ? ei[2 * j] : ei[(size_t)j];
}

// ---------------- dtype detect + CSR build ----------------

__global__ void init_counts_kernel(int* counts, int* fill, int N, int* flag) {
  int i = blockIdx.x * blockDim.x + threadIdx.x;
  if (i < N) { counts[i] = 1; fill[i] = 0; }  // 1 = self-loop
  if (i == 0) *flag = 1;                      // assume int64 until disproven
}

// nonzero odd int32 word => int32 storage. One atomic per wave (not per thread):
// 600k same-address atomics serialized ~6.8ms; ballot form is ~9.4k atomics.
__global__ void detect_kernel(const int* __restrict__ ei, int E, int* flag) {
  int i = blockIdx.x * blockDim.x + threadIdx.x;
  bool nz = (i < E) && (ei[2 * i + 1] != 0);
  if (__any(nz) && (threadIdx.x & 63) == 0) atomicAnd(flag, 0);
}

__global__ void count_kernel(const int* __restrict__ ei, int E,
                             const int* __restrict__ flag, int* __restrict__ counts) {
  int i = blockIdx.x * blockDim.x + threadIdx.x;
  if (i < E) {
    int d = eidx(ei, *flag, (long long)E + i);
    atomicAdd(&counts[d], 1);
  }
}

__global__ void scan_kernel(const int* __restrict__ counts, int* __restrict__ indptr, int N) {
  __shared__ int sums[256];
  __shared__ int offs[256];
  int t = threadIdx.x;
  int chunk = (N + 255) / 256;
  int lo = t * chunk;
  int hi = lo + chunk; if (hi > N) hi = N;
  int s = 0;
  for (int i = lo; i < hi; ++i) s += counts[i];
  sums[t] = s;
  __syncthreads();
  if (t == 0) {
    int acc = 0;
    for (int i = 0; i < 256; ++i) { offs[i] = acc; acc += sums[i]; }
    indptr[N] = acc;
  }
  __syncthreads();
  int acc = offs[t];
  for (int i = lo; i < hi; ++i) { indptr[i] = acc; acc += counts[i]; }
}

__global__ void fill_kernel(const int* __restrict__ ei, int E, int N,
                            const int* __restrict__ flag,
                            const int* __restrict__ indptr,
                            int* __restrict__ fill, int* __restrict__ csr_src,
                            int* __restrict__ csr_dst) {
  int i = blockIdx.x * blockDim.x + threadIdx.x;
  int total = E + N;
  if (i >= total) return;
  int s, d;
  if (i < E) { int f = *flag; s = eidx(ei, f, i); d = eidx(ei, f, (long long)E + i); }
  else       { s = i - E;  d = s; }
  int p = indptr[d] + atomicAdd(&fill[d], 1);
  csr_src[p] = s;
  csr_dst[p] = d;
}

__global__ void copy_kernel(const float* __restrict__ a, float* __restrict__ b, int n) {
  int i = blockIdx.x * blockDim.x + threadIdx.x;
  if (i < n) b[i] = a[i];
}

// ---------------- GEMM: Cl (+)= A@Wl, Cr (+)= A@Wr (mixed output types/strides) ------

template <typename TA, typename TCL, typename TCR, bool DUAL, bool ACCUM>
__global__ __launch_bounds__(256)
void gemm_kernel(const TA* __restrict__ A, int lda, int M, int K,
                 const float* __restrict__ Wl, const float* __restrict__ Wr,
                 int ldw, int Fc,
                 TCL* __restrict__ Cl, int ldcl, TCR* __restrict__ Cr, int ldcr) {
  __shared__ float As[BK][BM + 4];
  __shared__ float Bls[BK][BN];
  __shared__ float Brs[BK][BN];
  int tid = threadIdx.x;
  int tx = tid & 15, ty = tid >> 4;
  int bn = blockIdx.x * BN, bm = blockIdx.y * BM;
  float accl[4][4] = {};
  float accr[4][4] = {};
  for (int k0 = 0; k0 < K; k0 += BK) {
#pragma unroll
    for (int i = 0; i < 4; ++i) {
      int idx = tid + i * 256;
      int r = idx >> 4, c = idx & 15;
      int gr = bm + r, gc = k0 + c;
      As[c][r] = (gr < M && gc < K) ? ldf(&A[(size_t)gr * lda + gc]) : 0.f;
    }
#pragma unroll
    for (int i = 0; i < 4; ++i) {
      int idx = tid + i * 256;
      int c = idx >> 6, n = idx & 63;
      int gc = k0 + c, gn = bn + n;
      bool ok = (gc < K && gn < Fc);
      size_t w = (size_t)gc * ldw + gn;
      Bls[c][n] = ok ? Wl[w] : 0.f;
      if (DUAL) Brs[c][n] = ok ? Wr[w] : 0.f;
    }
    __syncthreads();
#pragma unroll
    for (int kk = 0; kk < BK; ++kk) {
      float4 a = *(const float4*)&As[kk][ty * 4];
      float4 bl = *(const float4*)&Bls[kk][tx * 4];
      float av[4] = {a.x, a.y, a.z, a.w};
      float blv[4] = {bl.x, bl.y, bl.z, bl.w};
      float brv[4] = {0.f, 0.f, 0.f, 0.f};
      if (DUAL) {
        float4 br = *(const float4*)&Brs[kk][tx * 4];
        brv[0] = br.x; brv[1] = br.y; brv[2] = br.z; brv[3] = br.w;
      }
#pragma unroll
      for (int i = 0; i < 4; ++i)
#pragma unroll
        for (int j = 0; j < 4; ++j) {
          accl[i][j] += av[i] * blv[j];
          if (DUAL) accr[i][j] += av[i] * brv[j];
        }
    }
    __syncthreads();
  }
#pragma unroll
  for (int i = 0; i < 4; ++i) {
    int gr = bm + ty * 4 + i;
    if (gr >= M) continue;
#pragma unroll
    for (int j = 0; j < 4; ++j) {
      int gn = bn + tx * 4 + j;
      if (gn >= Fc) continue;
      float vl = accl[i][j];
      size_t ol = (size_t)gr * ldcl + gn;
      if (ACCUM) vl += ldf(&Cl[ol]);
      stf(&Cl[ol], vl);
      if (DUAL) {
        float vr = accr[i][j];
        size_t orr = (size_t)gr * ldcr + gn;
        if (ACCUM) vr += ldf(&Cr[orr]);
        stf(&Cr[orr], vr);
      }
    }
  }
}

template <typename TA, typename TCL, typename TCR>
static void launch_gemm(const TA* A, int lda, int M, int K,
                        const float* Wl, const float* Wr, int ldw, int Fc,
                        TCL* Cl, int ldcl, TCR* Cr, int ldcr, bool accum, hipStream_t st) {
  dim3 grid((Fc + BN - 1) / BN, (M + BM - 1) / BM);
  if (Wr) {
    if (accum) gemm_kernel<TA, TCL, TCR, true, true><<<grid, 256, 0, st>>>(A, lda, M, K, Wl, Wr, ldw, Fc, Cl, ldcl, Cr, ldcr);
    else       gemm_kernel<TA, TCL, TCR, true, false><<<grid, 256, 0, st>>>(A, lda, M, K, Wl, Wr, ldw, Fc, Cl, ldcl, Cr, ldcr);
  } else {
    if (accum) gemm_kernel<TA, TCL, TCR, false, true><<<grid, 256, 0, st>>>(A, lda, M, K, Wl, Wl, ldw, Fc, Cl, ldcl, Cr, ldcr);
    else       gemm_kernel<TA, TCL, TCR, false, false><<<grid, 256, 0, st>>>(A, lda, M, K, Wl, Wl, ldw, Fc, Cl, ldcl, Cr, ldcr);
  }
}

// ---------------- edge scores (chunk-accumulating, mixed xl/xr types) ----------------

template <typename TSL, typename TSR, bool ACCUM>
__global__ void edge_e_kernel(const TSL* __restrict__ xl, int ldxl,
                              const TSR* __restrict__ xr, int ldxr,
                              const int* __restrict__ csr_src, const int* __restrict__ csr_dst,
                              const float* __restrict__ att, float* __restrict__ ev,
                              int Etot, int Fc) {
  int gid = blockIdx.x * blockDim.x + threadIdx.x;
  int edge = gid >> 6;
  int lane = threadIdx.x & 63;
  if (edge >= Etot) return;
  int s = csr_src[edge], d = csr_dst[edge];
  const TSL* pl = xl + (size_t)s * ldxl;
  const TSR* pr = xr + (size_t)d * ldxr;
  float acc = 0.f;
  for (int f = lane; f < Fc; f += 64) {
    float h = ldf(&pl[f]) + ldf(&pr[f]);
    h = h > 0.f ? h : NEG_SLOPE * h;
    acc += h * att[f];
  }
#pragma unroll
  for (int off = 32; off > 0; off >>= 1) acc += __shfl_down(acc, off);
  if (lane == 0) {
    if (ACCUM) ev[edge] += acc;
    else ev[edge] = acc;
  }
}

template <typename TSL, typename TSR>
static void launch_edge(const TSL* xl, int ldxl, const TSR* xr, int ldxr,
                        const int* cs, const int* cd,
                        const float* att, float* ev, int Etot, int Fc, bool accum,
                        hipStream_t st) {
  int blocks = (int)(((long long)Etot * 64 + 255) / 256);
  if (accum) edge_e_kernel<TSL, TSR, true><<<blocks, 256, 0, st>>>(xl, ldxl, xr, ldxr, cs, cd, att, ev, Etot, Fc);
  else       edge_e_kernel<TSL, TSR, false><<<blocks, 256, 0, st>>>(xl, ldxl, xr, ldxr, cs, cd, att, ev, Etot, Fc);
}

// ---------------- segment softmax (in-place e -> alpha) ----------------

__global__ void softmax_kernel(float* __restrict__ ev, const int* __restrict__ indptr, int N) {
  int i = blockIdx.x * blockDim.x + threadIdx.x;
  if (i >= N) return;
  int lo = indptr[i], hi = indptr[i + 1];
  float m = -1e30f;
  for (int j = lo; j < hi; ++j) m = fmaxf(m, ev[j]);
  float s = 0.f;
  for (int j = lo; j < hi; ++j) { float x = expf(ev[j] - m); ev[j] = x; s += x; }
  float inv = 1.f / s;
  for (int j = lo; j < hi; ++j) ev[j] *= inv;
}

// ---------------- aggregation over a feature chunk ----------------

template <int NC, typename TS, typename TD>
__global__ void aggregate_kernel(const TS* __restrict__ xl, int ldx,
                                 const float* __restrict__ alpha,
                                 const int* __restrict__ csr_src, const int* __restrict__ indptr,
                                 const float* __restrict__ bias,
                                 TD* __restrict__ out, int ldout, int N, int relu) {
  int gid = blockIdx.x * blockDim.x + threadIdx.x;
  int node = gid >> 6;
  int lane = threadIdx.x & 63;
  if (node >= N) return;
  float acc[NC];
#pragma unroll
  for (int c = 0; c < NC; ++c) acc[c] = bias[lane + c * 64];
  int lo = indptr[node], hi = indptr[node + 1];
  for (int j = lo; j < hi; ++j) {
    float a = alpha[j];
    const TS* row = xl + (size_t)csr_src[j] * ldx;
#pragma unroll
    for (int c = 0; c < NC; ++c) acc[c] += a * ldf(&row[lane + c * 64]);
  }
#pragma unroll
  for (int c = 0; c < NC; ++c) {
    float v = acc[c];
    if (relu) v = fmaxf(v, 0.f);
    stf(&out[(size_t)node * ldout + lane + c * 64], v);
  }
}

template <typename TS, typename TD>
static void launch_agg(const TS* xl, int ldx, const float* alpha, const int* cs, const int* ip,
                       const float* bias, TD* out, int ldout, int N, int Fc, int relu,
                       hipStream_t st) {
  int blocks = (int)(((long long)N * 64 + 255) / 256);
  switch (Fc >> 6) {
    case 8: aggregate_kernel<8, TS, TD><<<blocks, 256, 0, st>>>(xl, ldx, alpha, cs, ip, bias, out, ldout, N, relu); break;
    case 4: aggregate_kernel<4, TS, TD><<<blocks, 256, 0, st>>>(xl, ldx, alpha, cs, ip, bias, out, ldout, N, relu); break;
    case 2: aggregate_kernel<2, TS, TD><<<blocks, 256, 0, st>>>(xl, ldx, alpha, cs, ip, bias, out, ldout, N, relu); break;
  }
}

__global__ void aggregate3_kernel(const float* __restrict__ xl, const float* __restrict__ alpha,
                                  const int* __restrict__ csr_src, const int* __restrict__ indptr,
                                  const float* __restrict__ bias, float* __restrict__ out, int N) {
  int i = blockIdx.x * blockDim.x + threadIdx.x;
  if (i >= N) return;
  float a0 = bias[0], a1 = bias[1], a2 = bias[2];
  int lo = indptr[i], hi = indptr[i + 1];
  for (int j = lo; j < hi; ++j) {
    float a = alpha[j];
    const float* row = xl + (size_t)csr_src[j] * 3;
    a0 += a * row[0];
    a1 += a * row[1];
    a2 += a * row[2];
  }
  out[(size_t)i * 3 + 0] = a0;
  out[(size_t)i * 3 + 1] = a1;
  out[(size_t)i * 3 + 2] = a2;
}

// ---------------- launch ----------------

extern "C" void kernel_launch(void* const* d_in, const int* in_sizes, int n_in,
                              void* d_out, int out_size, void* d_ws, size_t ws_size,
                              hipStream_t stream) {
  const float* x = (const float*)d_in[0];
  const int* ei = (const int*)d_in[1];
  const int N = in_sizes[0] / 39;
  const int E = in_sizes[1] / 2;
  const int Etot = E + N;
  (void)n_in; (void)out_size;

  const float* Wl[5]; const float* Wr[5]; const float* att[5]; const float* bb[5];
  for (int l = 0; l < 5; ++l) {
    Wl[l]  = (const float*)d_in[2 + 4 * l];
    Wr[l]  = (const float*)d_in[3 + 4 * l];
    att[l] = (const float*)d_in[4 + 4 * l];
    bb[l]  = (const float*)d_in[5 + 4 * l];
  }

  char* ws = (char*)d_ws;
  size_t off = 0;
  auto alloc = [&](size_t b) -> char* {
    char* p = ws + off;
    off += (b + 255) & ~(size_t)255;
    return p;
  };
  int* counts  = (int*)alloc((size_t)N * 4);
  int* fillc   = (int*)alloc((size_t)N * 4);
  int* flag    = (int*)alloc(256);
  int* indptr  = (int*)alloc(((size_t)N + 1) * 4);
  int* csr_s   = (int*)alloc((size_t)Etot * 4);
  int* csr_d   = (int*)alloc((size_t)Etot * 4);
  float* ev    = (float*)alloc((size_t)Etot * 4);
  float* alpha1 = (float*)alloc((size_t)Etot * 4);
  size_t small_end = off;

  const size_t fat_need  = small_end + (size_t)N * (2048 + 3 * 512) + 4096;
  const size_t slim_need = small_end + (size_t)N * (256 + 256 + 3 * 512) + 4096;
  if (ws_size < slim_need) return;  // cannot run safely

  const int tb = 256;
  init_counts_kernel<<<(N + tb - 1) / tb, tb, 0, stream>>>(counts, fillc, N, flag);
  detect_kernel<<<(E + tb - 1) / tb, tb, 0, stream>>>(ei, E, flag);
  count_kernel<<<(E + tb - 1) / tb, tb, 0, stream>>>(ei, E, flag, counts);
  scan_kernel<<<1, 256, 0, stream>>>(counts, indptr, N);
  fill_kernel<<<(Etot + tb - 1) / tb, tb, 0, stream>>>(ei, E, N, flag, indptr,
                                                       fillc, csr_s, csr_d);

  if (ws_size >= fat_need) {
    // ================= FAT schedule: materialize out1 once =================
    char* F0 = alloc((size_t)N * 2048);  // out1 [N,1024]bf16 -> out2 [N,512]bf16
    char* F1 = alloc((size_t)N * 512);   // xl1c+t1 -> waccR fp32 -> out3 [N,256]bf16
    char* F2 = alloc((size_t)N * 512);   // XL2 low (spans F2+F3) -> XL3/XL4/XL5
    char* F3 = alloc((size_t)N * 512);   //                      -> XR3/XR4/XR5

    bf16* out1 = (bf16*)F0;
    bf16* xl1c = (bf16*)F1;
    bf16* t1   = (bf16*)(F1 + (size_t)N * 256);
    float* waccR = (float*)F1;
    bf16* XL2  = (bf16*)F2;  // [N,512] bf16, spans F2+F3 (contiguous)

    // ---- Layer 1 (39 -> 1024): scores, then materialize out1 ----
    for (int kc = 0; kc < 8; ++kc) {
      launch_gemm<float, bf16, bf16>(x, 39, N, 39, Wl[0] + kc * 128, Wr[0] + kc * 128, 1024, 128,
                                     xl1c, 128, t1, 128, false, stream);
      launch_edge<bf16, bf16>(xl1c, 128, t1, 128, csr_s, csr_d, att[0] + kc * 128, ev, Etot, 128, kc > 0, stream);
    }
    softmax_kernel<<<(N + tb - 1) / tb, tb, 0, stream>>>(ev, indptr, N);
    for (int kc = 0; kc < 8; ++kc) {
      launch_gemm<float, bf16, bf16>(x, 39, N, 39, Wl[0] + kc * 128, nullptr, 1024, 128,
                                     xl1c, 128, xl1c, 128, false, stream);
      launch_agg<bf16, bf16>(xl1c, 128, ev, csr_s, indptr, bb[0] + kc * 128,
                             out1 + kc * 128, 1024, N, 128, 1, stream);
    }

    // ---- Layer 2 (1024 -> 512): K=1024 GEMMs straight from out1 ----
    for (int fc = 0; fc < 4; ++fc) {
      launch_gemm<bf16, bf16, float>(out1, 1024, N, 1024, Wl[1] + fc * 128, Wr[1] + fc * 128,
                                     512, 128, XL2 + fc * 128, 512, waccR, 128, false, stream);
      launch_edge<bf16, float>(XL2 + fc * 128, 512, waccR, 128, csr_s, csr_d,
                               att[1] + fc * 128, ev, Etot, 128, fc > 0, stream);
    }
    softmax_kernel<<<(N + tb - 1) / tb, tb, 0, stream>>>(ev, indptr, N);
    bf16* out2 = (bf16*)F0;  // out1 dead after score GEMMs
    launch_agg<bf16, bf16>(XL2, 512, ev, csr_s, indptr, bb[1], out2, 512, N, 512, 1, stream);

    // ---- Layer 3 (512 -> 256) ----
    bf16* XL3 = (bf16*)F2;
    bf16* XR3 = (bf16*)F3;
    launch_gemm<bf16, bf16, bf16>(out2, 512, N, 512, Wl[2], Wr[2], 256, 256,
                                  XL3, 256, XR3, 256, false, stream);
    launch_edge<bf16, bf16>(XL3, 256, XR3, 256, csr_s, csr_d, att[2], ev, Etot, 256, false, stream);
    softmax_kernel<<<(N + tb - 1) / tb, tb, 0, stream>>>(ev, indptr, N);
    bf16* out3 = (bf16*)F1;
    launch_agg<bf16, bf16>(XL3, 256, ev, csr_s, indptr, bb[2], out3, 256, N, 256, 1, stream);

    // ---- Layer 4 (256 -> 128) -> d_out[0 : N*128] fp32 ----
    bf16* XL4 = (bf16*)F2;
    bf16* XR4 = (bf16*)F3;
    launch_gemm<bf16, bf16, bf16>(out3, 256, N, 256, Wl[3], Wr[3], 128, 128,
                                  XL4, 128, XR4, 128, false, stream);
    launch_edge<bf16, bf16>(XL4, 128, XR4, 128, csr_s, csr_d, att[3], ev, Etot, 128, false, stream);
    softmax_kernel<<<(N + tb - 1) / tb, tb, 0, stream>>>(ev, indptr, N);
    launch_agg<bf16, float>(XL4, 128, ev, csr_s, indptr, bb[3], (float*)d_out, 128, N, 128, 1, stream);

    // ---- Layer 5 (128 -> 3) -> coords fp32 ----
    float* XL5 = (float*)F2;
    float* XR5 = (float*)F3;
    launch_gemm<float, float, float>((const float*)d_out, 128, N, 128, Wl[4], Wr[4], 3, 3,
                                     XL5, 3, XR5, 3, false, stream);
    launch_edge<float, float>(XL5, 3, XR5, 3, csr_s, csr_d, att[4], ev, Etot, 3, false, stream);
    softmax_kernel<<<(N + tb - 1) / tb, tb, 0, stream>>>(ev, indptr, N);
    aggregate3_kernel<<<(N + tb - 1) / tb, tb, 0, stream>>>(XL5, ev, csr_s, indptr, bb[4],
                                                            (float*)d_out + (size_t)N * 128, N);
    return;
  }

  // ================= SLIM schedule (round-6 verified) =================
  char* R0 = alloc((size_t)N * 256);
  char* R1 = alloc((size_t)N * 256);
  char* R2 = alloc((size_t)N * 512);
  char* R3 = alloc((size_t)N * 512);
  char* R4 = alloc((size_t)N * 512);
  (void)R4;

  bf16* xl1c = (bf16*)R0;
  bf16* t1   = (bf16*)R1;
  float* waccL = (float*)R2;
  float* waccR = (float*)R3;
  bf16* out2 = (bf16*)R3;  // spans R3+R4

  for (int kc = 0; kc < 8; ++kc) {
    launch_gemm<float, bf16, bf16>(x, 39, N, 39, Wl[0] + kc * 128, Wr[0] + kc * 128, 1024, 128,
                                   xl1c, 128, t1, 128, false, stream);
    launch_edge<bf16, bf16>(xl1c, 128, t1, 128, csr_s, csr_d, att[0] + kc * 128, ev, Etot, 128, kc > 0, stream);
  }
  softmax_kernel<<<(N + tb - 1) / tb, tb, 0, stream>>>(ev, indptr, N);
  copy_kernel<<<(Etot + tb - 1) / tb, tb, 0, stream>>>(ev, alpha1, Etot);

  auto mat_out1 = [&](int kc) {
    launch_gemm<float, bf16, bf16>(x, 39, N, 39, Wl[0] + kc * 128, nullptr, 1024, 128,
                                   xl1c, 128, xl1c, 128, false, stream);
    launch_agg<bf16, bf16>(xl1c, 128, alpha1, csr_s, indptr, bb[0] + kc * 128,
                           t1, 128, N, 128, 1, stream);
  };

  for (int fc = 0; fc < 4; ++fc) {
    for (int kc = 0; kc < 8; ++kc) {
      mat_out1(kc);
      const float* wl = Wl[1] + (size_t)kc * 128 * 512 + fc * 128;
      const float* wr = Wr[1] + (size_t)kc * 128 * 512 + fc * 128;
      launch_gemm<bf16, float, float>(t1, 128, N, 128, wl, wr, 512, 128,
                                      waccL, 128, waccR, 128, kc > 0, stream);
    }
    launch_edge<float, float>(waccL, 128, waccR, 128, csr_s, csr_d, att[1] + fc * 128, ev, Etot, 128, fc > 0, stream);
  }
  softmax_kernel<<<(N + tb - 1) / tb, tb, 0, stream>>>(ev, indptr, N);
  for (int i = 0; i < 4; ++i) {
    int fc = (i == 0) ? 3 : (i - 1);   // fc=3 first: waccL still holds its XL chunk
    if (i > 0) {
      for (int kc = 0; kc < 8; ++kc) {
        mat_out1(kc);
        const float* wl = Wl[1] + (size_t)kc * 128 * 512 + fc * 128;
        launch_gemm<bf16, float, float>(t1, 128, N, 128, wl, nullptr, 512, 128,
                                        waccL, 128, waccL, 128, kc > 0, stream);
      }
    }
    launch_agg<float, bf16>(waccL, 128, ev, csr_s, indptr, bb[1] + fc * 128,
                            out2 + fc * 128, 512, N, 128, 1, stream);
  }

  bf16* XL3 = (bf16*)R2;
  bf16* XR3 = (bf16*)R0;  // spans R0+R1
  launch_gemm<bf16, bf16, bf16>(out2, 512, N, 512, Wl[2], Wr[2], 256, 256,
                                XL3, 256, XR3, 256, false, stream);
  launch_edge<bf16, bf16>(XL3, 256, XR3, 256, csr_s, csr_d, att[2], ev, Etot, 256, false, stream);
  softmax_kernel<<<(N + tb - 1) / tb, tb, 0, stream>>>(ev, indptr, N);
  bf16* out3 = XR3;
  launch_agg<bf16, bf16>(XL3, 256, ev, csr_s, indptr, bb[2], out3, 256, N, 256, 1, stream);

  bf16* XL4 = (bf16*)R2;
  bf16* XR4 = (bf16*)(R2 + (size_t)N * 256);
  launch_gemm<bf16, bf16, bf16>(out3, 256, N, 256, Wl[3], Wr[3], 128, 128,
                                XL4, 128, XR4, 128, false, stream);
  launch_edge<bf16, bf16>(XL4, 128, XR4, 128, csr_s, csr_d, att[3], ev, Etot, 128, false, stream);
  softmax_kernel<<<(N + tb - 1) / tb, tb, 0, stream>>>(ev, indptr, N);
  launch_agg<bf16, float>(XL4, 128, ev, csr_s, indptr, bb[3], (float*)d_out, 128, N, 128, 1, stream);

  float* XL5 = (float*)R3;
  float* XR5 = (float*)(R3 + (((size_t)N * 12 + 255) & ~(size_t)255));
  launch_gemm<float, float, float>((const float*)d_out, 128, N, 128, Wl[4], Wr[4], 3, 3,
                                   XL5, 3, XR5, 3, false, stream);
  launch_edge<float, float>(XL5, 3, XR5, 3, csr_s, csr_d, att[4], ev, Etot, 3, false, stream);
  softmax_kernel<<<(N + tb - 1) / tb, tb, 0, stream>>>(ev, indptr, N);
  aggregate3_kernel<<<(N + tb - 1) / tb, tb, 0, stream>>>(XL5, ev, csr_s, indptr, bb[4],
                                                          (float*)d_out + (size_t)N * 128, N);
}

// Round 8
// 17251.465 us; speedup vs baseline: 1.4126x; 1.0018x over previous
//
#include <hip/hip_runtime.h>
#include <hip/hip_bf16.h>
#include <math.h>

#define NEG_SLOPE 0.2f
#define BM 64
#define BN 64
#define BK 16

typedef __hip_bfloat16 bf16;
typedef __attribute__((ext_vector_type(8))) short sh8;
typedef __attribute__((ext_vector_type(4))) float f32x4;

__device__ __forceinline__ float ldf(const float* p) { return *p; }
__device__ __forceinline__ float ldf(const bf16* p) { return __bfloat162float(*p); }
__device__ __forceinline__ void stf(float* p, float v) { *p = v; }
__device__ __forceinline__ void stf(bf16* p, float v) { *p = __float2bfloat16(v); }

// pair load/store helpers (vectorized gathers)
__device__ __forceinline__ float2 ld2f(const bf16* p) {
  unsigned int u = *(const unsigned int*)p;
  float2 r;
  r.x = __uint_as_float((u & 0xffffu) << 16);
  r.y = __uint_as_float(u & 0xffff0000u);
  return r;
}
__device__ __forceinline__ float2 ld2f(const float* p) { return *(const float2*)p; }
__device__ __forceinline__ void st2f(bf16* p, float a, float b) {
  bf16 t[2] = { __float2bfloat16(a), __float2bfloat16(b) };
  *(unsigned int*)p = *(unsigned int*)t;
}
__device__ __forceinline__ void st2f(float* p, float a, float b) {
  float2 v; v.x = a; v.y = b; *(float2*)p = v;
}

// edge_index accessor: flat element j of the [2,E] array, robust to int32 vs int64 storage.
__device__ __forceinline__ int eidx(const int* __restrict__ ei, int f64, long long j) {
  return f64 ? ei[2 * j] : ei[(size_t)j];
}

// ---------------- dtype detect + CSR build ----------------

__global__ void init_counts_kernel(int* counts, int* fill, int N, int* flag) {
  int i = blockIdx.x * blockDim.x + threadIdx.x;
  if (i < N) { counts[i] = 1; fill[i] = 0; }  // 1 = self-loop
  if (i == 0) *flag = 1;                      // assume int64 until disproven
}

__global__ void detect_kernel(const int* __restrict__ ei, int E, int* flag) {
  int i = blockIdx.x * blockDim.x + threadIdx.x;
  bool nz = (i < E) && (ei[2 * i + 1] != 0);
  if (__any(nz) && (threadIdx.x & 63) == 0) atomicAnd(flag, 0);
}

__global__ void count_kernel(const int* __restrict__ ei, int E,
                             const int* __restrict__ flag, int* __restrict__ counts) {
  int i = blockIdx.x * blockDim.x + threadIdx.x;
  if (i < E) {
    int d = eidx(ei, *flag, (long long)E + i);
    atomicAdd(&counts[d], 1);
  }
}

__global__ void scan_kernel(const int* __restrict__ counts, int* __restrict__ indptr, int N) {
  __shared__ int sums[256];
  __shared__ int offs[256];
  int t = threadIdx.x;
  int chunk = (N + 255) / 256;
  int lo = t * chunk;
  int hi = lo + chunk; if (hi > N) hi = N;
  int s = 0;
  for (int i = lo; i < hi; ++i) s += counts[i];
  sums[t] = s;
  __syncthreads();
  if (t == 0) {
    int acc = 0;
    for (int i = 0; i < 256; ++i) { offs[i] = acc; acc += sums[i]; }
    indptr[N] = acc;
  }
  __syncthreads();
  int acc = offs[t];
  for (int i = lo; i < hi; ++i) { indptr[i] = acc; acc += counts[i]; }
}

__global__ void fill_kernel(const int* __restrict__ ei, int E, int N,
                            const int* __restrict__ flag,
                            const int* __restrict__ indptr,
                            int* __restrict__ fill, int* __restrict__ csr_src,
                            int* __restrict__ csr_dst) {
  int i = blockIdx.x * blockDim.x + threadIdx.x;
  int total = E + N;
  if (i >= total) return;
  int s, d;
  if (i < E) { int f = *flag; s = eidx(ei, f, i); d = eidx(ei, f, (long long)E + i); }
  else       { s = i - E;  d = s; }
  int p = indptr[d] + atomicAdd(&fill[d], 1);
  csr_src[p] = s;
  csr_dst[p] = d;
}

__global__ void copy_kernel(const float* __restrict__ a, float* __restrict__ b, int n) {
  int i = blockIdx.x * blockDim.x + threadIdx.x;
  if (i < n) b[i] = a[i];
}

// x [N,Kin] fp32 -> xb [N,Kp] bf16 zero-padded
__global__ void convert_pad_kernel(const float* __restrict__ x, bf16* __restrict__ xb, int N) {
  int i = blockIdx.x * blockDim.x + threadIdx.x;
  if (i >= N * 64) return;
  int n = i >> 6, c = i & 63;
  float v = (c < 39) ? x[(size_t)n * 39 + c] : 0.f;
  xb[i] = __float2bfloat16(v);
}

// ---------------- MFMA GEMM: Cl (+Cr) = A(bf16) @ W(fp32->bf16) ----------------
// Tile 128(M) x 64(N per side) x 32(K). 256 threads = 4 waves (2x2).
// A row-major [M,lda] bf16; W row-major [Kw,ldw] fp32 (rows >= Kw read as 0).
// LDS: A [128][40] bf16, B transposed [64][40] bf16 (stride 40 -> 16B aligned, low conflict).

template <bool DUAL, typename TCL, typename TCR>
__global__ __launch_bounds__(256)
void mfma_gemm_kernel(const bf16* __restrict__ A, int lda, int M, int K, int Kw,
                      const float* __restrict__ Wl, const float* __restrict__ Wr,
                      int ldw,
                      TCL* __restrict__ Cl, int ldcl, TCR* __restrict__ Cr, int ldcr) {
  __shared__ short As[128 * 40];
  __shared__ short Bls[64 * 40];
  __shared__ short Brs[64 * 40];
  int tid = threadIdx.x;
  int lane = tid & 63;
  int wave = tid >> 6;
  int wm = wave >> 1, wn = wave & 1;
  int bm = blockIdx.y * 128, bn = blockIdx.x * 64;
  f32x4 accl[4][2] = {};
  f32x4 accr[4][2] = {};
  int kg = lane >> 4;        // 0..3 (k-group of 8)
  int rr = lane & 15;

  for (int k0 = 0; k0 < K; k0 += 32) {
    // stage A: 512 chunks of 8 bf16; 2 per thread
#pragma unroll
    for (int i = 0; i < 2; ++i) {
      int c = tid + i * 256;
      int r = c >> 2, cg = c & 3;
      int gr = bm + r;
      uint4 u = make_uint4(0u, 0u, 0u, 0u);
      if (gr < M) u = *(const uint4*)(A + (size_t)gr * lda + k0 + cg * 8);
      *(uint4*)(As + r * 40 + cg * 8) = u;
    }
    // stage B transposed: thread -> col = tid&63, kblock = tid>>6 (8 k's)
    {
      int c = tid & 63, kb = tid >> 6;
      bf16 pl[8], pr[8];
#pragma unroll
      for (int j = 0; j < 8; ++j) {
        int kk = k0 + kb * 8 + j;
        float vl = 0.f, vr = 0.f;
        if (kk < Kw) {
          size_t w = (size_t)kk * ldw + bn + c;
          vl = Wl[w];
          if (DUAL) vr = Wr[w];
        }
        pl[j] = __float2bfloat16(vl);
        if (DUAL) pr[j] = __float2bfloat16(vr);
      }
      *(uint4*)(Bls + c * 40 + kb * 8) = *(uint4*)pl;
      if (DUAL) *(uint4*)(Brs + c * 40 + kb * 8) = *(uint4*)pr;
    }
    __syncthreads();
    // fragments + MFMA
    sh8 af[4], blf[2], brf[2];
#pragma unroll
    for (int mi = 0; mi < 4; ++mi)
      af[mi] = *(const sh8*)(As + (wm * 64 + mi * 16 + rr) * 40 + kg * 8);
#pragma unroll
    for (int ni = 0; ni < 2; ++ni) {
      blf[ni] = *(const sh8*)(Bls + (wn * 32 + ni * 16 + rr) * 40 + kg * 8);
      if (DUAL) brf[ni] = *(const sh8*)(Brs + (wn * 32 + ni * 16 + rr) * 40 + kg * 8);
    }
#pragma unroll
    for (int mi = 0; mi < 4; ++mi)
#pragma unroll
      for (int ni = 0; ni < 2; ++ni) {
        accl[mi][ni] = __builtin_amdgcn_mfma_f32_16x16x32_bf16(af[mi], blf[ni], accl[mi][ni], 0, 0, 0);
        if (DUAL)
          accr[mi][ni] = __builtin_amdgcn_mfma_f32_16x16x32_bf16(af[mi], brf[ni], accr[mi][ni], 0, 0, 0);
      }
    __syncthreads();
  }
  // epilogue: C[row][col], col = lane&15, row = (lane>>4)*4 + j
  int cr0 = (lane >> 4) * 4;
#pragma unroll
  for (int mi = 0; mi < 4; ++mi)
#pragma unroll
    for (int j = 0; j < 4; ++j) {
      int gr = bm + wm * 64 + mi * 16 + cr0 + j;
      if (gr >= M) continue;
#pragma unroll
      for (int ni = 0; ni < 2; ++ni) {
        int gc = bn + wn * 32 + ni * 16 + rr;
        stf(&Cl[(size_t)gr * ldcl + gc], accl[mi][ni][j]);
        if (DUAL) stf(&Cr[(size_t)gr * ldcr + gc], accr[mi][ni][j]);
      }
    }
}

template <bool DUAL, typename TCL, typename TCR>
static void launch_mfma(const bf16* A, int lda, int M, int K, int Kw,
                        const float* Wl, const float* Wr, int ldw, int Fc,
                        TCL* Cl, int ldcl, TCR* Cr, int ldcr, hipStream_t st) {
  dim3 grid(Fc / 64, (M + 127) / 128);
  mfma_gemm_kernel<DUAL, TCL, TCR><<<grid, 256, 0, st>>>(A, lda, M, K, Kw, Wl, Wr, ldw,
                                                         Cl, ldcl, Cr, ldcr);
}

// ---------------- vector GEMM (fp32 path, slim fallback + layer 5) ----------------

template <typename TA, typename TCL, typename TCR, bool DUAL, bool ACCUM>
__global__ __launch_bounds__(256)
void gemm_kernel(const TA* __restrict__ A, int lda, int M, int K,
                 const float* __restrict__ Wl, const float* __restrict__ Wr,
                 int ldw, int Fc,
                 TCL* __restrict__ Cl, int ldcl, TCR* __restrict__ Cr, int ldcr) {
  __shared__ float As[BK][BM + 4];
  __shared__ float Bls[BK][BN];
  __shared__ float Brs[BK][BN];
  int tid = threadIdx.x;
  int tx = tid & 15, ty = tid >> 4;
  int bn = blockIdx.x * BN, bm = blockIdx.y * BM;
  float accl[4][4] = {};
  float accr[4][4] = {};
  for (int k0 = 0; k0 < K; k0 += BK) {
#pragma unroll
    for (int i = 0; i < 4; ++i) {
      int idx = tid + i * 256;
      int r = idx >> 4, c = idx & 15;
      int gr = bm + r, gc = k0 + c;
      As[c][r] = (gr < M && gc < K) ? ldf(&A[(size_t)gr * lda + gc]) : 0.f;
    }
#pragma unroll
    for (int i = 0; i < 4; ++i) {
      int idx = tid + i * 256;
      int c = idx >> 6, n = idx & 63;
      int gc = k0 + c, gn = bn + n;
      bool ok = (gc < K && gn < Fc);
      size_t w = (size_t)gc * ldw + gn;
      Bls[c][n] = ok ? Wl[w] : 0.f;
      if (DUAL) Brs[c][n] = ok ? Wr[w] : 0.f;
    }
    __syncthreads();
#pragma unroll
    for (int kk = 0; kk < BK; ++kk) {
      float4 a = *(const float4*)&As[kk][ty * 4];
      float4 bl = *(const float4*)&Bls[kk][tx * 4];
      float av[4] = {a.x, a.y, a.z, a.w};
      float blv[4] = {bl.x, bl.y, bl.z, bl.w};
      float brv[4] = {0.f, 0.f, 0.f, 0.f};
      if (DUAL) {
        float4 br = *(const float4*)&Brs[kk][tx * 4];
        brv[0] = br.x; brv[1] = br.y; brv[2] = br.z; brv[3] = br.w;
      }
#pragma unroll
      for (int i = 0; i < 4; ++i)
#pragma unroll
        for (int j = 0; j < 4; ++j) {
          accl[i][j] += av[i] * blv[j];
          if (DUAL) accr[i][j] += av[i] * brv[j];
        }
    }
    __syncthreads();
  }
#pragma unroll
  for (int i = 0; i < 4; ++i) {
    int gr = bm + ty * 4 + i;
    if (gr >= M) continue;
#pragma unroll
    for (int j = 0; j < 4; ++j) {
      int gn = bn + tx * 4 + j;
      if (gn >= Fc) continue;
      float vl = accl[i][j];
      size_t ol = (size_t)gr * ldcl + gn;
      if (ACCUM) vl += ldf(&Cl[ol]);
      stf(&Cl[ol], vl);
      if (DUAL) {
        float vr = accr[i][j];
        size_t orr = (size_t)gr * ldcr + gn;
        if (ACCUM) vr += ldf(&Cr[orr]);
        stf(&Cr[orr], vr);
      }
    }
  }
}

template <typename TA, typename TCL, typename TCR>
static void launch_gemm(const TA* A, int lda, int M, int K,
                        const float* Wl, const float* Wr, int ldw, int Fc,
                        TCL* Cl, int ldcl, TCR* Cr, int ldcr, bool accum, hipStream_t st) {
  dim3 grid((Fc + BN - 1) / BN, (M + BM - 1) / BM);
  if (Wr) {
    if (accum) gemm_kernel<TA, TCL, TCR, true, true><<<grid, 256, 0, st>>>(A, lda, M, K, Wl, Wr, ldw, Fc, Cl, ldcl, Cr, ldcr);
    else       gemm_kernel<TA, TCL, TCR, true, false><<<grid, 256, 0, st>>>(A, lda, M, K, Wl, Wr, ldw, Fc, Cl, ldcl, Cr, ldcr);
  } else {
    if (accum) gemm_kernel<TA, TCL, TCR, false, true><<<grid, 256, 0, st>>>(A, lda, M, K, Wl, Wl, ldw, Fc, Cl, ldcl, Cr, ldcr);
    else       gemm_kernel<TA, TCL, TCR, false, false><<<grid, 256, 0, st>>>(A, lda, M, K, Wl, Wl, ldw, Fc, Cl, ldcl, Cr, ldcr);
  }
}

// ---------------- edge scores ----------------
// scalar version (Fc arbitrary; slim + layer 5)
template <typename TSL, typename TSR, bool ACCUM>
__global__ void edge_e_kernel(const TSL* __restrict__ xl, int ldxl,
                              const TSR* __restrict__ xr, int ldxr,
                              const int* __restrict__ csr_src, const int* __restrict__ csr_dst,
                              const float* __restrict__ att, float* __restrict__ ev,
                              int Etot, int Fc) {
  int gid = blockIdx.x * blockDim.x + threadIdx.x;
  int edge = gid >> 6;
  int lane = threadIdx.x & 63;
  if (edge >= Etot) return;
  int s = csr_src[edge], d = csr_dst[edge];
  const TSL* pl = xl + (size_t)s * ldxl;
  const TSR* pr = xr + (size_t)d * ldxr;
  float acc = 0.f;
  for (int f = lane; f < Fc; f += 64) {
    float h = ldf(&pl[f]) + ldf(&pr[f]);
    h = h > 0.f ? h : NEG_SLOPE * h;
    acc += h * att[f];
  }
#pragma unroll
  for (int off = 32; off > 0; off >>= 1) acc += __shfl_down(acc, off);
  if (lane == 0) {
    if (ACCUM) ev[edge] += acc;
    else ev[edge] = acc;
  }
}

template <typename TSL, typename TSR>
static void launch_edge(const TSL* xl, int ldxl, const TSR* xr, int ldxr,
                        const int* cs, const int* cd,
                        const float* att, float* ev, int Etot, int Fc, bool accum,
                        hipStream_t st) {
  int blocks = (int)(((long long)Etot * 64 + 255) / 256);
  if (accum) edge_e_kernel<TSL, TSR, true><<<blocks, 256, 0, st>>>(xl, ldxl, xr, ldxr, cs, cd, att, ev, Etot, Fc);
  else       edge_e_kernel<TSL, TSR, false><<<blocks, 256, 0, st>>>(xl, ldxl, xr, ldxr, cs, cd, att, ev, Etot, Fc);
}

// vectorized (Fc multiple of 128): lane handles feature pair (2*lane, 2*lane+1) per 128-block
template <typename TSL, typename TSR, bool ACCUM>
__global__ void edge_vec_kernel(const TSL* __restrict__ xl, int ldxl,
                                const TSR* __restrict__ xr, int ldxr,
                                const int* __restrict__ csr_src, const int* __restrict__ csr_dst,
                                const float* __restrict__ att, float* __restrict__ ev,
                                int Etot, int Fc) {
  int gid = blockIdx.x * blockDim.x + threadIdx.x;
  int edge = gid >> 6;
  int lane = threadIdx.x & 63;
  if (edge >= Etot) return;
  int s = csr_src[edge], d = csr_dst[edge];
  const TSL* pl = xl + (size_t)s * ldxl;
  const TSR* pr = xr + (size_t)d * ldxr;
  float acc = 0.f;
  for (int f = 2 * lane; f < Fc; f += 128) {
    float2 l = ld2f(pl + f);
    float2 r = ld2f(pr + f);
    float2 at = *(const float2*)(att + f);
    float h0 = l.x + r.x; h0 = h0 > 0.f ? h0 : NEG_SLOPE * h0;
    float h1 = l.y + r.y; h1 = h1 > 0.f ? h1 : NEG_SLOPE * h1;
    acc += h0 * at.x + h1 * at.y;
  }
#pragma unroll
  for (int off = 32; off > 0; off >>= 1) acc += __shfl_down(acc, off);
  if (lane == 0) {
    if (ACCUM) ev[edge] += acc;
    else ev[edge] = acc;
  }
}

template <typename TSL, typename TSR>
static void launch_edge_vec(const TSL* xl, int ldxl, const TSR* xr, int ldxr,
                            const int* cs, const int* cd,
                            const float* att, float* ev, int Etot, int Fc, bool accum,
                            hipStream_t st) {
  int blocks = (int)(((long long)Etot * 64 + 255) / 256);
  if (accum) edge_vec_kernel<TSL, TSR, true><<<blocks, 256, 0, st>>>(xl, ldxl, xr, ldxr, cs, cd, att, ev, Etot, Fc);
  else       edge_vec_kernel<TSL, TSR, false><<<blocks, 256, 0, st>>>(xl, ldxl, xr, ldxr, cs, cd, att, ev, Etot, Fc);
}

// ---------------- segment softmax (in-place e -> alpha) ----------------

__global__ void softmax_kernel(float* __restrict__ ev, const int* __restrict__ indptr, int N) {
  int i = blockIdx.x * blockDim.x + threadIdx.x;
  if (i >= N) return;
  int lo = indptr[i], hi = indptr[i + 1];
  float m = -1e30f;
  for (int j = lo; j < hi; ++j) m = fmaxf(m, ev[j]);
  float s = 0.f;
  for (int j = lo; j < hi; ++j) { float x = expf(ev[j] - m); ev[j] = x; s += x; }
  float inv = 1.f / s;
  for (int j = lo; j < hi; ++j) ev[j] *= inv;
}

// ---------------- aggregation ----------------
// scalar (slim fallback)
template <int NC, typename TS, typename TD>
__global__ void aggregate_kernel(const TS* __restrict__ xl, int ldx,
                                 const float* __restrict__ alpha,
                                 const int* __restrict__ csr_src, const int* __restrict__ indptr,
                                 const float* __restrict__ bias,
                                 TD* __restrict__ out, int ldout, int N, int relu) {
  int gid = blockIdx.x * blockDim.x + threadIdx.x;
  int node = gid >> 6;
  int lane = threadIdx.x & 63;
  if (node >= N) return;
  float acc[NC];
#pragma unroll
  for (int c = 0; c < NC; ++c) acc[c] = bias[lane + c * 64];
  int lo = indptr[node], hi = indptr[node + 1];
  for (int j = lo; j < hi; ++j) {
    float a = alpha[j];
    const TS* row = xl + (size_t)csr_src[j] * ldx;
#pragma unroll
    for (int c = 0; c < NC; ++c) acc[c] += a * ldf(&row[lane + c * 64]);
  }
#pragma unroll
  for (int c = 0; c < NC; ++c) {
    float v = acc[c];
    if (relu) v = fmaxf(v, 0.f);
    stf(&out[(size_t)node * ldout + lane + c * 64], v);
  }
}

template <typename TS, typename TD>
static void launch_agg(const TS* xl, int ldx, const float* alpha, const int* cs, const int* ip,
                       const float* bias, TD* out, int ldout, int N, int Fc, int relu,
                       hipStream_t st) {
  int blocks = (int)(((long long)N * 64 + 255) / 256);
  switch (Fc >> 6) {
    case 8: aggregate_kernel<8, TS, TD><<<blocks, 256, 0, st>>>(xl, ldx, alpha, cs, ip, bias, out, ldout, N, relu); break;
    case 4: aggregate_kernel<4, TS, TD><<<blocks, 256, 0, st>>>(xl, ldx, alpha, cs, ip, bias, out, ldout, N, relu); break;
    case 2: aggregate_kernel<2, TS, TD><<<blocks, 256, 0, st>>>(xl, ldx, alpha, cs, ip, bias, out, ldout, N, relu); break;
  }
}

// vectorized (Fc = NP*128): lane handles pair (2*lane, 2*lane+1) per 128-block
template <int NP, typename TS, typename TD>
__global__ void agg_vec_kernel(const TS* __restrict__ xl, int ldx,
                               const float* __restrict__ alpha,
                               const int* __restrict__ csr_src, const int* __restrict__ indptr,
                               const float* __restrict__ bias,
                               TD* __restrict__ out, int ldout, int N, int relu) {
  int gid = blockIdx.x * blockDim.x + threadIdx.x;
  int node = gid >> 6;
  int lane = threadIdx.x & 63;
  if (node >= N) return;
  float ax[NP], ay[NP];
#pragma unroll
  for (int p = 0; p < NP; ++p) {
    float2 b = *(const float2*)(bias + 2 * lane + p * 128);
    ax[p] = b.x; ay[p] = b.y;
  }
  int lo = indptr[node], hi = indptr[node + 1];
  for (int j = lo; j < hi; ++j) {
    float a = alpha[j];
    const TS* row = xl + (size_t)csr_src[j] * ldx;
#pragma unroll
    for (int p = 0; p < NP; ++p) {
      float2 v = ld2f(row + 2 * lane + p * 128);
      ax[p] += a * v.x;
      ay[p] += a * v.y;
    }
  }
#pragma unroll
  for (int p = 0; p < NP; ++p) {
    float vx = ax[p], vy = ay[p];
    if (relu) { vx = fmaxf(vx, 0.f); vy = fmaxf(vy, 0.f); }
    st2f(&out[(size_t)node * ldout + 2 * lane + p * 128], vx, vy);
  }
}

template <typename TS, typename TD>
static void launch_agg_vec(const TS* xl, int ldx, const float* alpha, const int* cs, const int* ip,
                           const float* bias, TD* out, int ldout, int N, int Fc, int relu,
                           hipStream_t st) {
  int blocks = (int)(((long long)N * 64 + 255) / 256);
  switch (Fc >> 7) {
    case 4: agg_vec_kernel<4, TS, TD><<<blocks, 256, 0, st>>>(xl, ldx, alpha, cs, ip, bias, out, ldout, N, relu); break;
    case 2: agg_vec_kernel<2, TS, TD><<<blocks, 256, 0, st>>>(xl, ldx, alpha, cs, ip, bias, out, ldout, N, relu); break;
    case 1: agg_vec_kernel<1, TS, TD><<<blocks, 256, 0, st>>>(xl, ldx, alpha, cs, ip, bias, out, ldout, N, relu); break;
  }
}

__global__ void aggregate3_kernel(const float* __restrict__ xl, const float* __restrict__ alpha,
                                  const int* __restrict__ csr_src, const int* __restrict__ indptr,
                                  const float* __restrict__ bias, float* __restrict__ out, int N) {
  int i = blockIdx.x * blockDim.x + threadIdx.x;
  if (i >= N) return;
  float a0 = bias[0], a1 = bias[1], a2 = bias[2];
  int lo = indptr[i], hi = indptr[i + 1];
  for (int j = lo; j < hi; ++j) {
    float a = alpha[j];
    const float* row = xl + (size_t)csr_src[j] * 3;
    a0 += a * row[0];
    a1 += a * row[1];
    a2 += a * row[2];
  }
  out[(size_t)i * 3 + 0] = a0;
  out[(size_t)i * 3 + 1] = a1;
  out[(size_t)i * 3 + 2] = a2;
}

// ---------------- launch ----------------

extern "C" void kernel_launch(void* const* d_in, const int* in_sizes, int n_in,
                              void* d_out, int out_size, void* d_ws, size_t ws_size,
                              hipStream_t stream) {
  const float* x = (const float*)d_in[0];
  const int* ei = (const int*)d_in[1];
  const int N = in_sizes[0] / 39;
  const int E = in_sizes[1] / 2;
  const int Etot = E + N;
  (void)n_in; (void)out_size;

  const float* Wl[5]; const float* Wr[5]; const float* att[5]; const float* bb[5];
  for (int l = 0; l < 5; ++l) {
    Wl[l]  = (const float*)d_in[2 + 4 * l];
    Wr[l]  = (const float*)d_in[3 + 4 * l];
    att[l] = (const float*)d_in[4 + 4 * l];
    bb[l]  = (const float*)d_in[5 + 4 * l];
  }

  char* ws = (char*)d_ws;
  size_t off = 0;
  auto alloc = [&](size_t b) -> char* {
    char* p = ws + off;
    off += (b + 255) & ~(size_t)255;
    return p;
  };
  int* counts  = (int*)alloc((size_t)N * 4);
  int* fillc   = (int*)alloc((size_t)N * 4);
  int* flag    = (int*)alloc(256);
  int* indptr  = (int*)alloc(((size_t)N + 1) * 4);
  int* csr_s   = (int*)alloc((size_t)Etot * 4);
  int* csr_d   = (int*)alloc((size_t)Etot * 4);
  float* ev    = (float*)alloc((size_t)Etot * 4);
  float* alpha1 = (float*)alloc((size_t)Etot * 4);
  size_t small_end = off;

  const size_t fat_need  = small_end + (size_t)N * (2048 + 3 * 512) + 4096;
  const size_t slim_need = small_end + (size_t)N * (256 + 256 + 3 * 512) + 4096;
  if (ws_size < slim_need) return;  // cannot run safely

  const int tb = 256;
  init_counts_kernel<<<(N + tb - 1) / tb, tb, 0, stream>>>(counts, fillc, N, flag);
  detect_kernel<<<(E + tb - 1) / tb, tb, 0, stream>>>(ei, E, flag);
  count_kernel<<<(E + tb - 1) / tb, tb, 0, stream>>>(ei, E, flag, counts);
  scan_kernel<<<1, 256, 0, stream>>>(counts, indptr, N);
  fill_kernel<<<(Etot + tb - 1) / tb, tb, 0, stream>>>(ei, E, N, flag, indptr,
                                                       fillc, csr_s, csr_d);

  if (ws_size >= fat_need) {
    // ================= FAT schedule (MFMA GEMMs) =================
    char* F0 = alloc((size_t)N * 2048);  // out1 [N,1024]bf16 -> out2 [N,512]bf16
    char* F1 = alloc((size_t)N * 512);   // xl1c+t1 -> waccR fp32 -> out3 [N,256]bf16
    char* F2 = alloc((size_t)N * 512);   // xpad [N,64]bf16 -> XL2 low -> XL3/XL4/XL5
    char* F3 = alloc((size_t)N * 512);   // XL2 high -> XR3/XR4/XR5

    bf16* out1 = (bf16*)F0;
    bf16* xl1c = (bf16*)F1;
    bf16* t1   = (bf16*)(F1 + (size_t)N * 256);
    float* waccR = (float*)F1;
    bf16* xpad = (bf16*)F2;  // [N,64] bf16 zero-padded x (dead before XL2 is written)
    bf16* XL2  = (bf16*)F2;  // [N,512] bf16 spans F2+F3

    convert_pad_kernel<<<(N * 64 + tb - 1) / tb, tb, 0, stream>>>(x, xpad, N);

    // ---- Layer 1 (39 -> 1024): scores, then materialize out1 ----
    for (int kc = 0; kc < 8; ++kc) {
      launch_mfma<true, bf16, bf16>(xpad, 64, N, 64, 39, Wl[0] + kc * 128, Wr[0] + kc * 128,
                                    1024, 128, xl1c, 128, t1, 128, stream);
      launch_edge_vec<bf16, bf16>(xl1c, 128, t1, 128, csr_s, csr_d, att[0] + kc * 128,
                                  ev, Etot, 128, kc > 0, stream);
    }
    softmax_kernel<<<(N + tb - 1) / tb, tb, 0, stream>>>(ev, indptr, N);
    for (int kc = 0; kc < 8; ++kc) {
      launch_mfma<false, bf16, bf16>(xpad, 64, N, 64, 39, Wl[0] + kc * 128, Wl[0] + kc * 128,
                                     1024, 128, xl1c, 128, t1, 128, stream);
      launch_agg_vec<bf16, bf16>(xl1c, 128, ev, csr_s, indptr, bb[0] + kc * 128,
                                 out1 + kc * 128, 1024, N, 128, 1, stream);
    }

    // ---- Layer 2 (1024 -> 512) ----
    for (int fc = 0; fc < 4; ++fc) {
      launch_mfma<true, bf16, float>(out1, 1024, N, 1024, 1024, Wl[1] + fc * 128, Wr[1] + fc * 128,
                                     512, 128, XL2 + fc * 128, 512, waccR, 128, stream);
      launch_edge_vec<bf16, float>(XL2 + fc * 128, 512, waccR, 128, csr_s, csr_d,
                                   att[1] + fc * 128, ev, Etot, 128, fc > 0, stream);
    }
    softmax_kernel<<<(N + tb - 1) / tb, tb, 0, stream>>>(ev, indptr, N);
    bf16* out2 = (bf16*)F0;  // out1 dead after score GEMMs
    launch_agg_vec<bf16, bf16>(XL2, 512, ev, csr_s, indptr, bb[1], out2, 512, N, 512, 1, stream);

    // ---- Layer 3 (512 -> 256) ----
    bf16* XL3 = (bf16*)F2;
    bf16* XR3 = (bf16*)F3;
    launch_mfma<true, bf16, bf16>(out2, 512, N, 512, 512, Wl[2], Wr[2], 256, 256,
                                  XL3, 256, XR3, 256, stream);
    launch_edge_vec<bf16, bf16>(XL3, 256, XR3, 256, csr_s, csr_d, att[2], ev, Etot, 256, false, stream);
    softmax_kernel<<<(N + tb - 1) / tb, tb, 0, stream>>>(ev, indptr, N);
    bf16* out3 = (bf16*)F1;
    launch_agg_vec<bf16, bf16>(XL3, 256, ev, csr_s, indptr, bb[2], out3, 256, N, 256, 1, stream);

    // ---- Layer 4 (256 -> 128) -> d_out[0 : N*128] fp32 ----
    bf16* XL4 = (bf16*)F2;
    bf16* XR4 = (bf16*)F3;
    launch_mfma<true, bf16, bf16>(out3, 256, N, 256, 256, Wl[3], Wr[3], 128, 128,
                                  XL4, 128, XR4, 128, stream);
    launch_edge_vec<bf16, bf16>(XL4, 128, XR4, 128, csr_s, csr_d, att[3], ev, Etot, 128, false, stream);
    softmax_kernel<<<(N + tb - 1) / tb, tb, 0, stream>>>(ev, indptr, N);
    launch_agg_vec<bf16, float>(XL4, 128, ev, csr_s, indptr, bb[3], (float*)d_out, 128, N, 128, 1, stream);

    // ---- Layer 5 (128 -> 3) -> coords fp32 ----
    float* XL5 = (float*)F2;
    float* XR5 = (float*)F3;
    launch_gemm<float, float, float>((const float*)d_out, 128, N, 128, Wl[4], Wr[4], 3, 3,
                                     XL5, 3, XR5, 3, false, stream);
    launch_edge<float, float>(XL5, 3, XR5, 3, csr_s, csr_d, att[4], ev, Etot, 3, false, stream);
    softmax_kernel<<<(N + tb - 1) / tb, tb, 0, stream>>>(ev, indptr, N);
    aggregate3_kernel<<<(N + tb - 1) / tb, tb, 0, stream>>>(XL5, ev, csr_s, indptr, bb[4],
                                                            (float*)d_out + (size_t)N * 128, N);
    return;
  }

  // ================= SLIM schedule (round-6 verified, fp32 vector GEMM) =================
  char* R0 = alloc((size_t)N * 256);
  char* R1 = alloc((size_t)N * 256);
  char* R2 = alloc((size_t)N * 512);
  char* R3 = alloc((size_t)N * 512);
  char* R4 = alloc((size_t)N * 512);
  (void)R4;

  bf16* xl1c = (bf16*)R0;
  bf16* t1   = (bf16*)R1;
  float* waccL = (float*)R2;
  float* waccR = (float*)R3;
  bf16* out2 = (bf16*)R3;  // spans R3+R4

  for (int kc = 0; kc < 8; ++kc) {
    launch_gemm<float, bf16, bf16>(x, 39, N, 39, Wl[0] + kc * 128, Wr[0] + kc * 128, 1024, 128,
                                   xl1c, 128, t1, 128, false, stream);
    launch_edge<bf16, bf16>(xl1c, 128, t1, 128, csr_s, csr_d, att[0] + kc * 128, ev, Etot, 128, kc > 0, stream);
  }
  softmax_kernel<<<(N + tb - 1) / tb, tb, 0, stream>>>(ev, indptr, N);
  copy_kernel<<<(Etot + tb - 1) / tb, tb, 0, stream>>>(ev, alpha1, Etot);

  auto mat_out1 = [&](int kc) {
    launch_gemm<float, bf16, bf16>(x, 39, N, 39, Wl[0] + kc * 128, nullptr, 1024, 128,
                                   xl1c, 128, xl1c, 128, false, stream);
    launch_agg<bf16, bf16>(xl1c, 128, alpha1, csr_s, indptr, bb[0] + kc * 128,
                           t1, 128, N, 128, 1, stream);
  };

  for (int fc = 0; fc < 4; ++fc) {
    for (int kc = 0; kc < 8; ++kc) {
      mat_out1(kc);
      const float* wl = Wl[1] + (size_t)kc * 128 * 512 + fc * 128;
      const float* wr = Wr[1] + (size_t)kc * 128 * 512 + fc * 128;
      launch_gemm<bf16, float, float>(t1, 128, N, 128, wl, wr, 512, 128,
                                      waccL, 128, waccR, 128, kc > 0, stream);
    }
    launch_edge<float, float>(waccL, 128, waccR, 128, csr_s, csr_d, att[1] + fc * 128, ev, Etot, 128, fc > 0, stream);
  }
  softmax_kernel<<<(N + tb - 1) / tb, tb, 0, stream>>>(ev, indptr, N);
  for (int i = 0; i < 4; ++i) {
    int fc = (i == 0) ? 3 : (i - 1);
    if (i > 0) {
      for (int kc = 0; kc < 8; ++kc) {
        mat_out1(kc);
        const float* wl = Wl[1] + (size_t)kc * 128 * 512 + fc * 128;
        launch_gemm<bf16, float, float>(t1, 128, N, 128, wl, nullptr, 512, 128,
                                        waccL, 128, waccL, 128, kc > 0, stream);
      }
    }
    launch_agg<float, bf16>(waccL, 128, ev, csr_s, indptr, bb[1] + fc * 128,
                            out2 + fc * 128, 512, N, 128, 1, stream);
  }

  bf16* XL3 = (bf16*)R2;
  bf16* XR3 = (bf16*)R0;
  launch_gemm<bf16, bf16, bf16>(out2, 512, N, 512, Wl[2], Wr[2], 256, 256,
                                XL3, 256, XR3, 256, false, stream);
  launch_edge<bf16, bf16>(XL3, 256, XR3, 256, csr_s, csr_d, att[2], ev, Etot, 256, false, stream);
  softmax_kernel<<<(N + tb - 1) / tb, tb, 0, stream>>>(ev, indptr, N);
  bf16* out3 = XR3;
  launch_agg<bf16, bf16>(XL3, 256, ev, csr_s, indptr, bb[2], out3, 256, N, 256, 1, stream);

  bf16* XL4 = (bf16*)R2;
  bf16* XR4 = (bf16*)(R2 + (size_t)N * 256);
  launch_gemm<bf16, bf16, bf16>(out3, 256, N, 256, Wl[3], Wr[3], 128, 128,
                                XL4, 128, XR4, 128, false, stream);
  launch_edge<bf16, bf16>(XL4, 128, XR4, 128, csr_s, csr_d, att[3], ev, Etot, 128, false, stream);
  softmax_kernel<<<(N + tb - 1) / tb, tb, 0, stream>>>(ev, indptr, N);
  launch_agg<bf16, float>(XL4, 128, ev, csr_s, indptr, bb[3], (float*)d_out, 128, N, 128, 1, stream);

  float* XL5 = (float*)R3;
  float* XR5 = (float*)(R3 + (((size_t)N * 12 + 255) & ~(size_t)255));
  launch_gemm<float, float, float>((const float*)d_out, 128, N, 128, Wl[4], Wr[4], 3, 3,
                                   XL5, 3, XR5, 3, false, stream);
  launch_edge<float, float>(XL5, 3, XR5, 3, csr_s, csr_d, att[4], ev, Etot, 3, false, stream);
  softmax_kernel<<<(N + tb - 1) / tb, tb, 0, stream>>>(ev, indptr, N);
  aggregate3_kernel<<<(N + tb - 1) / tb, tb, 0, stream>>>(XL5, ev, csr_s, indptr, bb[4],
                                                          (float*)d_out + (size_t)N * 128, N);
}

// Round 9
// 17061.185 us; speedup vs baseline: 1.4283x; 1.0112x over previous
//
#include <hip/hip_runtime.h>
#include <hip/hip_bf16.h>
#include <math.h>

#define NEG_SLOPE 0.2f
#define BM 64
#define BN 64
#define BK 16

typedef __hip_bfloat16 bf16;
typedef __attribute__((ext_vector_type(8))) short sh8;
typedef __attribute__((ext_vector_type(4))) float f32x4;

__device__ __forceinline__ float ldf(const float* p) { return *p; }
__device__ __forceinline__ float ldf(const bf16* p) { return __bfloat162float(*p); }
__device__ __forceinline__ void stf(float* p, float v) { *p = v; }
__device__ __forceinline__ void stf(bf16* p, float v) { *p = __float2bfloat16(v); }

// pair load/store helpers (vectorized gathers)
__device__ __forceinline__ float2 ld2f(const bf16* p) {
  unsigned int u = *(const unsigned int*)p;
  float2 r;
  r.x = __uint_as_float((u & 0xffffu) << 16);
  r.y = __uint_as_float(u & 0xffff0000u);
  return r;
}
__device__ __forceinline__ float2 ld2f(const float* p) { return *(const float2*)p; }
__device__ __forceinline__ void st2f(bf16* p, float a, float b) {
  bf16 t[2] = { __float2bfloat16(a), __float2bfloat16(b) };
  *(unsigned int*)p = *(unsigned int*)t;
}
__device__ __forceinline__ void st2f(float* p, float a, float b) {
  float2 v; v.x = a; v.y = b; *(float2*)p = v;
}

// edge_index accessor: flat element j of the [2,E] array, robust to int32 vs int64 storage.
__device__ __forceinline__ int eidx(const int* __restrict__ ei, int f64, long long j) {
  return f64 ? ei[2 * j] : ei[(size_t)j];
}

// ---------------- dtype detect + CSR build ----------------

__global__ void init_counts_kernel(int* counts, int* fill, int N, int* flag) {
  int i = blockIdx.x * blockDim.x + threadIdx.x;
  if (i < N) { counts[i] = 1; fill[i] = 0; }  // 1 = self-loop
  if (i == 0) *flag = 1;                      // assume int64 until disproven
}

__global__ void detect_kernel(const int* __restrict__ ei, int E, int* flag) {
  int i = blockIdx.x * blockDim.x + threadIdx.x;
  bool nz = (i < E) && (ei[2 * i + 1] != 0);
  if (__any(nz) && (threadIdx.x & 63) == 0) atomicAnd(flag, 0);
}

__global__ void count_kernel(const int* __restrict__ ei, int E,
                             const int* __restrict__ flag, int* __restrict__ counts) {
  int i = blockIdx.x * blockDim.x + threadIdx.x;
  if (i < E) {
    int d = eidx(ei, *flag, (long long)E + i);
    atomicAdd(&counts[d], 1);
  }
}

__global__ void scan_kernel(const int* __restrict__ counts, int* __restrict__ indptr, int N) {
  __shared__ int sums[256];
  __shared__ int offs[256];
  int t = threadIdx.x;
  int chunk = (N + 255) / 256;
  int lo = t * chunk;
  int hi = lo + chunk; if (hi > N) hi = N;
  int s = 0;
  for (int i = lo; i < hi; ++i) s += counts[i];
  sums[t] = s;
  __syncthreads();
  if (t == 0) {
    int acc = 0;
    for (int i = 0; i < 256; ++i) { offs[i] = acc; acc += sums[i]; }
    indptr[N] = acc;
  }
  __syncthreads();
  int acc = offs[t];
  for (int i = lo; i < hi; ++i) { indptr[i] = acc; acc += counts[i]; }
}

__global__ void fill_kernel(const int* __restrict__ ei, int E, int N,
                            const int* __restrict__ flag,
                            const int* __restrict__ indptr,
                            int* __restrict__ fill, int* __restrict__ csr_src,
                            int* __restrict__ csr_dst) {
  int i = blockIdx.x * blockDim.x + threadIdx.x;
  int total = E + N;
  if (i >= total) return;
  int s, d;
  if (i < E) { int f = *flag; s = eidx(ei, f, i); d = eidx(ei, f, (long long)E + i); }
  else       { s = i - E;  d = s; }
  int p = indptr[d] + atomicAdd(&fill[d], 1);
  csr_src[p] = s;
  csr_dst[p] = d;
}

__global__ void copy_kernel(const float* __restrict__ a, float* __restrict__ b, int n) {
  int i = blockIdx.x * blockDim.x + threadIdx.x;
  if (i < n) b[i] = a[i];
}

// x [N,39] fp32 -> xb [N,64] bf16 zero-padded
__global__ void convert_pad_kernel(const float* __restrict__ x, bf16* __restrict__ xb, int N) {
  int i = blockIdx.x * blockDim.x + threadIdx.x;
  if (i >= N * 64) return;
  int n = i >> 6, c = i & 63;
  float v = (c < 39) ? x[(size_t)n * 39 + c] : 0.f;
  xb[i] = __float2bfloat16(v);
}

// ---------------- MFMA GEMM: Cl (+Cr) = A(bf16) @ W(fp32->bf16) ----------------
// Tile 128(M) x 64(N per side) x 32(K). 256 threads = 4 waves (2x2).
// A row-major [M,lda] bf16; W row-major [Kw,ldw] fp32 (rows >= Kw read as 0).
// LDS: A [128][40] bf16, B transposed [64][40] bf16 (stride 40 -> 16B aligned, low conflict).

template <bool DUAL, typename TCL, typename TCR>
__global__ __launch_bounds__(256)
void mfma_gemm_kernel(const bf16* __restrict__ A, int lda, int M, int K, int Kw,
                      const float* __restrict__ Wl, const float* __restrict__ Wr,
                      int ldw,
                      TCL* __restrict__ Cl, int ldcl, TCR* __restrict__ Cr, int ldcr) {
  __shared__ short As[128 * 40];
  __shared__ short Bls[64 * 40];
  __shared__ short Brs[64 * 40];
  int tid = threadIdx.x;
  int lane = tid & 63;
  int wave = tid >> 6;
  int wm = wave >> 1, wn = wave & 1;
  int bm = blockIdx.y * 128, bn = blockIdx.x * 64;
  f32x4 accl[4][2] = {};
  f32x4 accr[4][2] = {};
  int kg = lane >> 4;        // 0..3 (k-group of 8)
  int rr = lane & 15;

  for (int k0 = 0; k0 < K; k0 += 32) {
    // stage A: 512 chunks of 8 bf16; 2 per thread
#pragma unroll
    for (int i = 0; i < 2; ++i) {
      int c = tid + i * 256;
      int r = c >> 2, cg = c & 3;
      int gr = bm + r;
      uint4 u = make_uint4(0u, 0u, 0u, 0u);
      if (gr < M) u = *(const uint4*)(A + (size_t)gr * lda + k0 + cg * 8);
      *(uint4*)(As + r * 40 + cg * 8) = u;
    }
    // stage B transposed: thread -> col = tid&63, kblock = tid>>6 (8 k's)
    {
      int c = tid & 63, kb = tid >> 6;
      bf16 pl[8], pr[8];
#pragma unroll
      for (int j = 0; j < 8; ++j) {
        int kk = k0 + kb * 8 + j;
        float vl = 0.f, vr = 0.f;
        if (kk < Kw) {
          size_t w = (size_t)kk * ldw + bn + c;
          vl = Wl[w];
          if (DUAL) vr = Wr[w];
        }
        pl[j] = __float2bfloat16(vl);
        if (DUAL) pr[j] = __float2bfloat16(vr);
      }
      *(uint4*)(Bls + c * 40 + kb * 8) = *(uint4*)pl;
      if (DUAL) *(uint4*)(Brs + c * 40 + kb * 8) = *(uint4*)pr;
    }
    __syncthreads();
    // fragments + MFMA
    sh8 af[4], blf[2], brf[2];
#pragma unroll
    for (int mi = 0; mi < 4; ++mi)
      af[mi] = *(const sh8*)(As + (wm * 64 + mi * 16 + rr) * 40 + kg * 8);
#pragma unroll
    for (int ni = 0; ni < 2; ++ni) {
      blf[ni] = *(const sh8*)(Bls + (wn * 32 + ni * 16 + rr) * 40 + kg * 8);
      if (DUAL) brf[ni] = *(const sh8*)(Brs + (wn * 32 + ni * 16 + rr) * 40 + kg * 8);
    }
#pragma unroll
    for (int mi = 0; mi < 4; ++mi)
#pragma unroll
      for (int ni = 0; ni < 2; ++ni) {
        accl[mi][ni] = __builtin_amdgcn_mfma_f32_16x16x32_bf16(af[mi], blf[ni], accl[mi][ni], 0, 0, 0);
        if (DUAL)
          accr[mi][ni] = __builtin_amdgcn_mfma_f32_16x16x32_bf16(af[mi], brf[ni], accr[mi][ni], 0, 0, 0);
      }
    __syncthreads();
  }
  // epilogue: C[row][col], col = lane&15, row = (lane>>4)*4 + j
  int cr0 = (lane >> 4) * 4;
#pragma unroll
  for (int mi = 0; mi < 4; ++mi)
#pragma unroll
    for (int j = 0; j < 4; ++j) {
      int gr = bm + wm * 64 + mi * 16 + cr0 + j;
      if (gr >= M) continue;
#pragma unroll
      for (int ni = 0; ni < 2; ++ni) {
        int gc = bn + wn * 32 + ni * 16 + rr;
        stf(&Cl[(size_t)gr * ldcl + gc], accl[mi][ni][j]);
        if (DUAL) stf(&Cr[(size_t)gr * ldcr + gc], accr[mi][ni][j]);
      }
    }
}

template <bool DUAL, typename TCL, typename TCR>
static void launch_mfma(const bf16* A, int lda, int M, int K, int Kw,
                        const float* Wl, const float* Wr, int ldw, int Fc,
                        TCL* Cl, int ldcl, TCR* Cr, int ldcr, hipStream_t st) {
  dim3 grid(Fc / 64, (M + 127) / 128);
  mfma_gemm_kernel<DUAL, TCL, TCR><<<grid, 256, 0, st>>>(A, lda, M, K, Kw, Wl, Wr, ldw,
                                                         Cl, ldcl, Cr, ldcr);
}

// ---------------- vector GEMM (fp32 path, slim fallback + layer 5) ----------------
// renamed vgemm_kernel: a "gemm_kernel" row in the profile now proves a stale binary.

template <typename TA, typename TCL, typename TCR, bool DUAL, bool ACCUM>
__global__ __launch_bounds__(256)
void vgemm_kernel(const TA* __restrict__ A, int lda, int M, int K,
                  const float* __restrict__ Wl, const float* __restrict__ Wr,
                  int ldw, int Fc,
                  TCL* __restrict__ Cl, int ldcl, TCR* __restrict__ Cr, int ldcr) {
  __shared__ float As[BK][BM + 4];
  __shared__ float Bls[BK][BN];
  __shared__ float Brs[BK][BN];
  int tid = threadIdx.x;
  int tx = tid & 15, ty = tid >> 4;
  int bn = blockIdx.x * BN, bm = blockIdx.y * BM;
  float accl[4][4] = {};
  float accr[4][4] = {};
  for (int k0 = 0; k0 < K; k0 += BK) {
#pragma unroll
    for (int i = 0; i < 4; ++i) {
      int idx = tid + i * 256;
      int r = idx >> 4, c = idx & 15;
      int gr = bm + r, gc = k0 + c;
      As[c][r] = (gr < M && gc < K) ? ldf(&A[(size_t)gr * lda + gc]) : 0.f;
    }
#pragma unroll
    for (int i = 0; i < 4; ++i) {
      int idx = tid + i * 256;
      int c = idx >> 6, n = idx & 63;
      int gc = k0 + c, gn = bn + n;
      bool ok = (gc < K && gn < Fc);
      size_t w = (size_t)gc * ldw + gn;
      Bls[c][n] = ok ? Wl[w] : 0.f;
      if (DUAL) Brs[c][n] = ok ? Wr[w] : 0.f;
    }
    __syncthreads();
#pragma unroll
    for (int kk = 0; kk < BK; ++kk) {
      float4 a = *(const float4*)&As[kk][ty * 4];
      float4 bl = *(const float4*)&Bls[kk][tx * 4];
      float av[4] = {a.x, a.y, a.z, a.w};
      float blv[4] = {bl.x, bl.y, bl.z, bl.w};
      float brv[4] = {0.f, 0.f, 0.f, 0.f};
      if (DUAL) {
        float4 br = *(const float4*)&Brs[kk][tx * 4];
        brv[0] = br.x; brv[1] = br.y; brv[2] = br.z; brv[3] = br.w;
      }
#pragma unroll
      for (int i = 0; i < 4; ++i)
#pragma unroll
        for (int j = 0; j < 4; ++j) {
          accl[i][j] += av[i] * blv[j];
          if (DUAL) accr[i][j] += av[i] * brv[j];
        }
    }
    __syncthreads();
  }
#pragma unroll
  for (int i = 0; i < 4; ++i) {
    int gr = bm + ty * 4 + i;
    if (gr >= M) continue;
#pragma unroll
    for (int j = 0; j < 4; ++j) {
      int gn = bn + tx * 4 + j;
      if (gn >= Fc) continue;
      float vl = accl[i][j];
      size_t ol = (size_t)gr * ldcl + gn;
      if (ACCUM) vl += ldf(&Cl[ol]);
      stf(&Cl[ol], vl);
      if (DUAL) {
        float vr = accr[i][j];
        size_t orr = (size_t)gr * ldcr + gn;
        if (ACCUM) vr += ldf(&Cr[orr]);
        stf(&Cr[orr], vr);
      }
    }
  }
}

template <typename TA, typename TCL, typename TCR>
static void launch_vgemm(const TA* A, int lda, int M, int K,
                         const float* Wl, const float* Wr, int ldw, int Fc,
                         TCL* Cl, int ldcl, TCR* Cr, int ldcr, bool accum, hipStream_t st) {
  dim3 grid((Fc + BN - 1) / BN, (M + BM - 1) / BM);
  if (Wr) {
    if (accum) vgemm_kernel<TA, TCL, TCR, true, true><<<grid, 256, 0, st>>>(A, lda, M, K, Wl, Wr, ldw, Fc, Cl, ldcl, Cr, ldcr);
    else       vgemm_kernel<TA, TCL, TCR, true, false><<<grid, 256, 0, st>>>(A, lda, M, K, Wl, Wr, ldw, Fc, Cl, ldcl, Cr, ldcr);
  } else {
    if (accum) vgemm_kernel<TA, TCL, TCR, false, true><<<grid, 256, 0, st>>>(A, lda, M, K, Wl, Wl, ldw, Fc, Cl, ldcl, Cr, ldcr);
    else       vgemm_kernel<TA, TCL, TCR, false, false><<<grid, 256, 0, st>>>(A, lda, M, K, Wl, Wl, ldw, Fc, Cl, ldcl, Cr, ldcr);
  }
}

// ---------------- edge scores ----------------

template <typename TSL, typename TSR, bool ACCUM>
__global__ void edge_e_kernel(const TSL* __restrict__ xl, int ldxl,
                              const TSR* __restrict__ xr, int ldxr,
                              const int* __restrict__ csr_src, const int* __restrict__ csr_dst,
                              const float* __restrict__ att, float* __restrict__ ev,
                              int Etot, int Fc) {
  int gid = blockIdx.x * blockDim.x + threadIdx.x;
  int edge = gid >> 6;
  int lane = threadIdx.x & 63;
  if (edge >= Etot) return;
  int s = csr_src[edge], d = csr_dst[edge];
  const TSL* pl = xl + (size_t)s * ldxl;
  const TSR* pr = xr + (size_t)d * ldxr;
  float acc = 0.f;
  for (int f = lane; f < Fc; f += 64) {
    float h = ldf(&pl[f]) + ldf(&pr[f]);
    h = h > 0.f ? h : NEG_SLOPE * h;
    acc += h * att[f];
  }
#pragma unroll
  for (int off = 32; off > 0; off >>= 1) acc += __shfl_down(acc, off);
  if (lane == 0) {
    if (ACCUM) ev[edge] += acc;
    else ev[edge] = acc;
  }
}

template <typename TSL, typename TSR>
static void launch_edge(const TSL* xl, int ldxl, const TSR* xr, int ldxr,
                        const int* cs, const int* cd,
                        const float* att, float* ev, int Etot, int Fc, bool accum,
                        hipStream_t st) {
  int blocks = (int)(((long long)Etot * 64 + 255) / 256);
  if (accum) edge_e_kernel<TSL, TSR, true><<<blocks, 256, 0, st>>>(xl, ldxl, xr, ldxr, cs, cd, att, ev, Etot, Fc);
  else       edge_e_kernel<TSL, TSR, false><<<blocks, 256, 0, st>>>(xl, ldxl, xr, ldxr, cs, cd, att, ev, Etot, Fc);
}

// vectorized (Fc multiple of 128): lane handles feature pair (2*lane, 2*lane+1) per 128-block
template <typename TSL, typename TSR, bool ACCUM>
__global__ void edge_vec_kernel(const TSL* __restrict__ xl, int ldxl,
                                const TSR* __restrict__ xr, int ldxr,
                                const int* __restrict__ csr_src, const int* __restrict__ csr_dst,
                                const float* __restrict__ att, float* __restrict__ ev,
                                int Etot, int Fc) {
  int gid = blockIdx.x * blockDim.x + threadIdx.x;
  int edge = gid >> 6;
  int lane = threadIdx.x & 63;
  if (edge >= Etot) return;
  int s = csr_src[edge], d = csr_dst[edge];
  const TSL* pl = xl + (size_t)s * ldxl;
  const TSR* pr = xr + (size_t)d * ldxr;
  float acc = 0.f;
  for (int f = 2 * lane; f < Fc; f += 128) {
    float2 l = ld2f(pl + f);
    float2 r = ld2f(pr + f);
    float2 at = *(const float2*)(att + f);
    float h0 = l.x + r.x; h0 = h0 > 0.f ? h0 : NEG_SLOPE * h0;
    float h1 = l.y + r.y; h1 = h1 > 0.f ? h1 : NEG_SLOPE * h1;
    acc += h0 * at.x + h1 * at.y;
  }
#pragma unroll
  for (int off = 32; off > 0; off >>= 1) acc += __shfl_down(acc, off);
  if (lane == 0) {
    if (ACCUM) ev[edge] += acc;
    else ev[edge] = acc;
  }
}

template <typename TSL, typename TSR>
static void launch_edge_vec(const TSL* xl, int ldxl, const TSR* xr, int ldxr,
                            const int* cs, const int* cd,
                            const float* att, float* ev, int Etot, int Fc, bool accum,
                            hipStream_t st) {
  int blocks = (int)(((long long)Etot * 64 + 255) / 256);
  if (accum) edge_vec_kernel<TSL, TSR, true><<<blocks, 256, 0, st>>>(xl, ldxl, xr, ldxr, cs, cd, att, ev, Etot, Fc);
  else       edge_vec_kernel<TSL, TSR, false><<<blocks, 256, 0, st>>>(xl, ldxl, xr, ldxr, cs, cd, att, ev, Etot, Fc);
}

// ---------------- segment softmax (in-place e -> alpha) ----------------

__global__ void softmax_kernel(float* __restrict__ ev, const int* __restrict__ indptr, int N) {
  int i = blockIdx.x * blockDim.x + threadIdx.x;
  if (i >= N) return;
  int lo = indptr[i], hi = indptr[i + 1];
  float m = -1e30f;
  for (int j = lo; j < hi; ++j) m = fmaxf(m, ev[j]);
  float s = 0.f;
  for (int j = lo; j < hi; ++j) { float x = expf(ev[j] - m); ev[j] = x; s += x; }
  float inv = 1.f / s;
  for (int j = lo; j < hi; ++j) ev[j] *= inv;
}

// ---------------- aggregation ----------------

template <int NC, typename TS, typename TD>
__global__ void aggregate_kernel(const TS* __restrict__ xl, int ldx,
                                 const float* __restrict__ alpha,
                                 const int* __restrict__ csr_src, const int* __restrict__ indptr,
                                 const float* __restrict__ bias,
                                 TD* __restrict__ out, int ldout, int N, int relu) {
  int gid = blockIdx.x * blockDim.x + threadIdx.x;
  int node = gid >> 6;
  int lane = threadIdx.x & 63;
  if (node >= N) return;
  float acc[NC];
#pragma unroll
  for (int c = 0; c < NC; ++c) acc[c] = bias[lane + c * 64];
  int lo = indptr[node], hi = indptr[node + 1];
  for (int j = lo; j < hi; ++j) {
    float a = alpha[j];
    const TS* row = xl + (size_t)csr_src[j] * ldx;
#pragma unroll
    for (int c = 0; c < NC; ++c) acc[c] += a * ldf(&row[lane + c * 64]);
  }
#pragma unroll
  for (int c = 0; c < NC; ++c) {
    float v = acc[c];
    if (relu) v = fmaxf(v, 0.f);
    stf(&out[(size_t)node * ldout + lane + c * 64], v);
  }
}

template <typename TS, typename TD>
static void launch_agg(const TS* xl, int ldx, const float* alpha, const int* cs, const int* ip,
                       const float* bias, TD* out, int ldout, int N, int Fc, int relu,
                       hipStream_t st) {
  int blocks = (int)(((long long)N * 64 + 255) / 256);
  switch (Fc >> 6) {
    case 8: aggregate_kernel<8, TS, TD><<<blocks, 256, 0, st>>>(xl, ldx, alpha, cs, ip, bias, out, ldout, N, relu); break;
    case 4: aggregate_kernel<4, TS, TD><<<blocks, 256, 0, st>>>(xl, ldx, alpha, cs, ip, bias, out, ldout, N, relu); break;
    case 2: aggregate_kernel<2, TS, TD><<<blocks, 256, 0, st>>>(xl, ldx, alpha, cs, ip, bias, out, ldout, N, relu); break;
  }
}

// vectorized (Fc = NP*128): lane handles pair (2*lane, 2*lane+1) per 128-block
template <int NP, typename TS, typename TD>
__global__ void agg_vec_kernel(const TS* __restrict__ xl, int ldx,
                               const float* __restrict__ alpha,
                               const int* __restrict__ csr_src, const int* __restrict__ indptr,
                               const float* __restrict__ bias,
                               TD* __restrict__ out, int ldout, int N, int relu) {
  int gid = blockIdx.x * blockDim.x + threadIdx.x;
  int node = gid >> 6;
  int lane = threadIdx.x & 63;
  if (node >= N) return;
  float ax[NP], ay[NP];
#pragma unroll
  for (int p = 0; p < NP; ++p) {
    float2 b = *(const float2*)(bias + 2 * lane + p * 128);
    ax[p] = b.x; ay[p] = b.y;
  }
  int lo = indptr[node], hi = indptr[node + 1];
  for (int j = lo; j < hi; ++j) {
    float a = alpha[j];
    const TS* row = xl + (size_t)csr_src[j] * ldx;
#pragma unroll
    for (int p = 0; p < NP; ++p) {
      float2 v = ld2f(row + 2 * lane + p * 128);
      ax[p] += a * v.x;
      ay[p] += a * v.y;
    }
  }
#pragma unroll
  for (int p = 0; p < NP; ++p) {
    float vx = ax[p], vy = ay[p];
    if (relu) { vx = fmaxf(vx, 0.f); vy = fmaxf(vy, 0.f); }
    st2f(&out[(size_t)node * ldout + 2 * lane + p * 128], vx, vy);
  }
}

template <typename TS, typename TD>
static void launch_agg_vec(const TS* xl, int ldx, const float* alpha, const int* cs, const int* ip,
                           const float* bias, TD* out, int ldout, int N, int Fc, int relu,
                           hipStream_t st) {
  int blocks = (int)(((long long)N * 64 + 255) / 256);
  switch (Fc >> 7) {
    case 4: agg_vec_kernel<4, TS, TD><<<blocks, 256, 0, st>>>(xl, ldx, alpha, cs, ip, bias, out, ldout, N, relu); break;
    case 2: agg_vec_kernel<2, TS, TD><<<blocks, 256, 0, st>>>(xl, ldx, alpha, cs, ip, bias, out, ldout, N, relu); break;
    case 1: agg_vec_kernel<1, TS, TD><<<blocks, 256, 0, st>>>(xl, ldx, alpha, cs, ip, bias, out, ldout, N, relu); break;
  }
}

__global__ void aggregate3_kernel(const float* __restrict__ xl, const float* __restrict__ alpha,
                                  const int* __restrict__ csr_src, const int* __restrict__ indptr,
                                  const float* __restrict__ bias, float* __restrict__ out, int N) {
  int i = blockIdx.x * blockDim.x + threadIdx.x;
  if (i >= N) return;
  float a0 = bias[0], a1 = bias[1], a2 = bias[2];
  int lo = indptr[i], hi = indptr[i + 1];
  for (int j = lo; j < hi; ++j) {
    float a = alpha[j];
    const float* row = xl + (size_t)csr_src[j] * 3;
    a0 += a * row[0];
    a1 += a * row[1];
    a2 += a * row[2];
  }
  out[(size_t)i * 3 + 0] = a0;
  out[(size_t)i * 3 + 1] = a1;
  out[(size_t)i * 3 + 2] = a2;
}

// ---------------- launch ----------------

extern "C" void kernel_launch(void* const* d_in, const int* in_sizes, int n_in,
                              void* d_out, int out_size, void* d_ws, size_t ws_size,
                              hipStream_t stream) {
  const float* x = (const float*)d_in[0];
  const int* ei = (const int*)d_in[1];
  const int N = in_sizes[0] / 39;
  const int E = in_sizes[1] / 2;
  const int Etot = E + N;
  (void)n_in; (void)out_size;

  const float* Wl[5]; const float* Wr[5]; const float* att[5]; const float* bb[5];
  for (int l = 0; l < 5; ++l) {
    Wl[l]  = (const float*)d_in[2 + 4 * l];
    Wr[l]  = (const float*)d_in[3 + 4 * l];
    att[l] = (const float*)d_in[4 + 4 * l];
    bb[l]  = (const float*)d_in[5 + 4 * l];
  }

  char* ws = (char*)d_ws;
  size_t off = 0;
  auto alloc = [&](size_t b) -> char* {
    char* p = ws + off;
    off += (b + 255) & ~(size_t)255;
    return p;
  };
  int* counts  = (int*)alloc((size_t)N * 4);
  int* fillc   = (int*)alloc((size_t)N * 4);
  int* flag    = (int*)alloc(256);
  int* indptr  = (int*)alloc(((size_t)N + 1) * 4);
  int* csr_s   = (int*)alloc((size_t)Etot * 4);
  int* csr_d   = (int*)alloc((size_t)Etot * 4);
  float* ev    = (float*)alloc((size_t)Etot * 4);
  float* alpha1 = (float*)alloc((size_t)Etot * 4);
  size_t small_end = off;

  const size_t fat_need  = small_end + (size_t)N * (2048 + 3 * 512) + 4096;
  const size_t slim_need = small_end + (size_t)N * (256 + 256 + 3 * 512) + 4096;
  if (ws_size < slim_need) return;  // cannot run safely

  const int tb = 256;
  init_counts_kernel<<<(N + tb - 1) / tb, tb, 0, stream>>>(counts, fillc, N, flag);
  detect_kernel<<<(E + tb - 1) / tb, tb, 0, stream>>>(ei, E, flag);
  count_kernel<<<(E + tb - 1) / tb, tb, 0, stream>>>(ei, E, flag, counts);
  scan_kernel<<<1, 256, 0, stream>>>(counts, indptr, N);
  fill_kernel<<<(Etot + tb - 1) / tb, tb, 0, stream>>>(ei, E, N, flag, indptr,
                                                       fillc, csr_s, csr_d);

  if (ws_size >= fat_need) {
    // ================= FAT schedule (MFMA GEMMs) =================
    char* F0 = alloc((size_t)N * 2048);  // out1 [N,1024]bf16 -> out2 [N,512]bf16
    char* F1 = alloc((size_t)N * 512);   // xl1c+t1 -> waccR fp32 -> out3 [N,256]bf16
    char* F2 = alloc((size_t)N * 512);   // xpad [N,64]bf16 -> XL2 low -> XL3/XL4/XL5
    char* F3 = alloc((size_t)N * 512);   // XL2 high -> XR3/XR4/XR5

    bf16* out1 = (bf16*)F0;
    bf16* xl1c = (bf16*)F1;
    bf16* t1   = (bf16*)(F1 + (size_t)N * 256);
    float* waccR = (float*)F1;
    bf16* xpad = (bf16*)F2;  // [N,64] bf16 zero-padded x (dead before XL2 is written)
    bf16* XL2  = (bf16*)F2;  // [N,512] bf16 spans F2+F3

    convert_pad_kernel<<<(N * 64 + tb - 1) / tb, tb, 0, stream>>>(x, xpad, N);

    // ---- Layer 1 (39 -> 1024): scores, then materialize out1 ----
    for (int kc = 0; kc < 8; ++kc) {
      launch_mfma<true, bf16, bf16>(xpad, 64, N, 64, 39, Wl[0] + kc * 128, Wr[0] + kc * 128,
                                    1024, 128, xl1c, 128, t1, 128, stream);
      launch_edge_vec<bf16, bf16>(xl1c, 128, t1, 128, csr_s, csr_d, att[0] + kc * 128,
                                  ev, Etot, 128, kc > 0, stream);
    }
    softmax_kernel<<<(N + tb - 1) / tb, tb, 0, stream>>>(ev, indptr, N);
    for (int kc = 0; kc < 8; ++kc) {
      launch_mfma<false, bf16, bf16>(xpad, 64, N, 64, 39, Wl[0] + kc * 128, Wl[0] + kc * 128,
                                     1024, 128, xl1c, 128, t1, 128, stream);
      launch_agg_vec<bf16, bf16>(xl1c, 128, ev, csr_s, indptr, bb[0] + kc * 128,
                                 out1 + kc * 128, 1024, N, 128, 1, stream);
    }

    // ---- Layer 2 (1024 -> 512) ----
    for (int fc = 0; fc < 4; ++fc) {
      launch_mfma<true, bf16, float>(out1, 1024, N, 1024, 1024, Wl[1] + fc * 128, Wr[1] + fc * 128,
                                     512, 128, XL2 + fc * 128, 512, waccR, 128, stream);
      launch_edge_vec<bf16, float>(XL2 + fc * 128, 512, waccR, 128, csr_s, csr_d,
                                   att[1] + fc * 128, ev, Etot, 128, fc > 0, stream);
    }
    softmax_kernel<<<(N + tb - 1) / tb, tb, 0, stream>>>(ev, indptr, N);
    bf16* out2 = (bf16*)F0;  // out1 dead after score GEMMs
    launch_agg_vec<bf16, bf16>(XL2, 512, ev, csr_s, indptr, bb[1], out2, 512, N, 512, 1, stream);

    // ---- Layer 3 (512 -> 256) ----
    bf16* XL3 = (bf16*)F2;
    bf16* XR3 = (bf16*)F3;
    launch_mfma<true, bf16, bf16>(out2, 512, N, 512, 512, Wl[2], Wr[2], 256, 256,
                                  XL3, 256, XR3, 256, stream);
    launch_edge_vec<bf16, bf16>(XL3, 256, XR3, 256, csr_s, csr_d, att[2], ev, Etot, 256, false, stream);
    softmax_kernel<<<(N + tb - 1) / tb, tb, 0, stream>>>(ev, indptr, N);
    bf16* out3 = (bf16*)F1;
    launch_agg_vec<bf16, bf16>(XL3, 256, ev, csr_s, indptr, bb[2], out3, 256, N, 256, 1, stream);

    // ---- Layer 4 (256 -> 128) -> d_out[0 : N*128] fp32 ----
    bf16* XL4 = (bf16*)F2;
    bf16* XR4 = (bf16*)F3;
    launch_mfma<true, bf16, bf16>(out3, 256, N, 256, 256, Wl[3], Wr[3], 128, 128,
                                  XL4, 128, XR4, 128, stream);
    launch_edge_vec<bf16, bf16>(XL4, 128, XR4, 128, csr_s, csr_d, att[3], ev, Etot, 128, false, stream);
    softmax_kernel<<<(N + tb - 1) / tb, tb, 0, stream>>>(ev, indptr, N);
    launch_agg_vec<bf16, float>(XL4, 128, ev, csr_s, indptr, bb[3], (float*)d_out, 128, N, 128, 1, stream);

    // ---- Layer 5 (128 -> 3) -> coords fp32 ----
    float* XL5 = (float*)F2;
    float* XR5 = (float*)F3;
    launch_vgemm<float, float, float>((const float*)d_out, 128, N, 128, Wl[4], Wr[4], 3, 3,
                                      XL5, 3, XR5, 3, false, stream);
    launch_edge<float, float>(XL5, 3, XR5, 3, csr_s, csr_d, att[4], ev, Etot, 3, false, stream);
    softmax_kernel<<<(N + tb - 1) / tb, tb, 0, stream>>>(ev, indptr, N);
    aggregate3_kernel<<<(N + tb - 1) / tb, tb, 0, stream>>>(XL5, ev, csr_s, indptr, bb[4],
                                                            (float*)d_out + (size_t)N * 128, N);
    return;
  }

  // ================= SLIM schedule (round-6 verified, fp32 vector GEMM) =================
  char* R0 = alloc((size_t)N * 256);
  char* R1 = alloc((size_t)N * 256);
  char* R2 = alloc((size_t)N * 512);
  char* R3 = alloc((size_t)N * 512);
  char* R4 = alloc((size_t)N * 512);
  (void)R4;

  bf16* xl1c = (bf16*)R0;
  bf16* t1   = (bf16*)R1;
  float* waccL = (float*)R2;
  float* waccR = (float*)R3;
  bf16* out2 = (bf16*)R3;  // spans R3+R4

  for (int kc = 0; kc < 8; ++kc) {
    launch_vgemm<float, bf16, bf16>(x, 39, N, 39, Wl[0] + kc * 128, Wr[0] + kc * 128, 1024, 128,
                                    xl1c, 128, t1, 128, false, stream);
    launch_edge<bf16, bf16>(xl1c, 128, t1, 128, csr_s, csr_d, att[0] + kc * 128, ev, Etot, 128, kc > 0, stream);
  }
  softmax_kernel<<<(N + tb - 1) / tb, tb, 0, stream>>>(ev, indptr, N);
  copy_kernel<<<(Etot + tb - 1) / tb, tb, 0, stream>>>(ev, alpha1, Etot);

  auto mat_out1 = [&](int kc) {
    launch_vgemm<float, bf16, bf16>(x, 39, N, 39, Wl[0] + kc * 128, nullptr, 1024, 128,
                                    xl1c, 128, xl1c, 128, false, stream);
    launch_agg<bf16, bf16>(xl1c, 128, alpha1, csr_s, indptr, bb[0] + kc * 128,
                           t1, 128, N, 128, 1, stream);
  };

  for (int fc = 0; fc < 4; ++fc) {
    for (int kc = 0; kc < 8; ++kc) {
      mat_out1(kc);
      const float* wl = Wl[1] + (size_t)kc * 128 * 512 + fc * 128;
      const float* wr = Wr[1] + (size_t)kc * 128 * 512 + fc * 128;
      launch_vgemm<bf16, float, float>(t1, 128, N, 128, wl, wr, 512, 128,
                                       waccL, 128, waccR, 128, kc > 0, stream);
    }
    launch_edge<float, float>(waccL, 128, waccR, 128, csr_s, csr_d, att[1] + fc * 128, ev, Etot, 128, fc > 0, stream);
  }
  softmax_kernel<<<(N + tb - 1) / tb, tb, 0, stream>>>(ev, indptr, N);
  for (int i = 0; i < 4; ++i) {
    int fc = (i == 0) ? 3 : (i - 1);
    if (i > 0) {
      for (int kc = 0; kc < 8; ++kc) {
        mat_out1(kc);
        const float* wl = Wl[1] + (size_t)kc * 128 * 512 + fc * 128;
        launch_vgemm<bf16, float, float>(t1, 128, N, 128, wl, nullptr, 512, 128,
                                         waccL, 128, waccL, 128, kc > 0, stream);
      }
    }
    launch_agg<float, bf16>(waccL, 128, ev, csr_s, indptr, bb[1] + fc * 128,
                            out2 + fc * 128, 512, N, 128, 1, stream);
  }

  bf16* XL3 = (bf16*)R2;
  bf16* XR3 = (bf16*)R0;
  launch_vgemm<bf16, bf16, bf16>(out2, 512, N, 512, Wl[2], Wr[2], 256, 256,
                                 XL3, 256, XR3, 256, false, stream);
  launch_edge<bf16, bf16>(XL3, 256, XR3, 256, csr_s, csr_d, att[2], ev, Etot, 256, false, stream);
  softmax_kernel<<<(N + tb - 1) / tb, tb, 0, stream>>>(ev, indptr, N);
  bf16* out3 = XR3;
  launch_agg<bf16, bf16>(XL3, 256, ev, csr_s, indptr, bb[2], out3, 256, N, 256, 1, stream);

  bf16* XL4 = (bf16*)R2;
  bf16* XR4 = (bf16*)(R2 + (size_t)N * 256);
  launch_vgemm<bf16, bf16, bf16>(out3, 256, N, 256, Wl[3], Wr[3], 128, 128,
                                 XL4, 128, XR4, 128, false, stream);
  launch_edge<bf16, bf16>(XL4, 128, XR4, 128, csr_s, csr_d, att[3], ev, Etot, 128, false, stream);
  softmax_kernel<<<(N + tb - 1) / tb, tb, 0, stream>>>(ev, indptr, N);
  launch_agg<bf16, float>(XL4, 128, ev, csr_s, indptr, bb[3], (float*)d_out, 128, N, 128, 1, stream);

  float* XL5 = (float*)R3;
  float* XR5 = (float*)(R3 + (((size_t)N * 12 + 255) & ~(size_t)255));
  launch_vgemm<float, float, float>((const float*)d_out, 128, N, 128, Wl[4], Wr[4], 3, 3,
                                    XL5, 3, XR5, 3, false, stream);
  launch_edge<float, float>(XL5, 3, XR5, 3, csr_s, csr_d, att[4], ev, Etot, 3, false, stream);
  softmax_kernel<<<(N + tb - 1) / tb, tb, 0, stream>>>(ev, indptr, N);
  aggregate3_kernel<<<(N + tb - 1) / tb, tb, 0, stream>>>(XL5, ev, csr_s, indptr, bb[4],
                                                          (float*)d_out + (size_t)N * 128, N);
}

// Round 10
// 12474.348 us; speedup vs baseline: 1.9535x; 1.3677x over previous
//
#include <hip/hip_runtime.h>
#include <hip/hip_bf16.h>
#include <math.h>

#define NEG_SLOPE 0.2f
#define BM 64
#define BN 64
#define BK 16

typedef __hip_bfloat16 bf16;
typedef __attribute__((ext_vector_type(8))) short sh8;
typedef __attribute__((ext_vector_type(4))) float f32x4;

__device__ __forceinline__ float ldf(const float* p) { return *p; }
__device__ __forceinline__ float ldf(const bf16* p) { return __bfloat162float(*p); }
__device__ __forceinline__ void stf(float* p, float v) { *p = v; }
__device__ __forceinline__ void stf(bf16* p, float v) { *p = __float2bfloat16(v); }

__device__ __forceinline__ float2 ld2f(const bf16* p) {
  unsigned int u = *(const unsigned int*)p;
  float2 r;
  r.x = __uint_as_float((u & 0xffffu) << 16);
  r.y = __uint_as_float(u & 0xffff0000u);
  return r;
}
__device__ __forceinline__ float2 ld2f(const float* p) { return *(const float2*)p; }
__device__ __forceinline__ void st2f(bf16* p, float a, float b) {
  bf16 t[2] = { __float2bfloat16(a), __float2bfloat16(b) };
  *(unsigned int*)p = *(unsigned int*)t;
}
__device__ __forceinline__ void st2f(float* p, float a, float b) {
  float2 v; v.x = a; v.y = b; *(float2*)p = v;
}

__device__ __forceinline__ int eidx(const int* __restrict__ ei, int f64, long long j) {
  return f64 ? ei[2 * j] : ei[(size_t)j];
}

// ---------------- dtype detect + CSR build ----------------

__global__ void init_counts_kernel(int* counts, int* fill, int N, int* flag) {
  int i = blockIdx.x * blockDim.x + threadIdx.x;
  if (i < N) { counts[i] = 1; fill[i] = 0; }
  if (i == 0) *flag = 1;
}

__global__ void detect_kernel(const int* __restrict__ ei, int E, int* flag) {
  int i = blockIdx.x * blockDim.x + threadIdx.x;
  bool nz = (i < E) && (ei[2 * i + 1] != 0);
  if (__any(nz) && (threadIdx.x & 63) == 0) atomicAnd(flag, 0);
}

__global__ void count_kernel(const int* __restrict__ ei, int E,
                             const int* __restrict__ flag, int* __restrict__ counts) {
  int i = blockIdx.x * blockDim.x + threadIdx.x;
  if (i < E) {
    int d = eidx(ei, *flag, (long long)E + i);
    atomicAdd(&counts[d], 1);
  }
}

__global__ void scan_kernel(const int* __restrict__ counts, int* __restrict__ indptr, int N) {
  __shared__ int sums[256];
  __shared__ int offs[256];
  int t = threadIdx.x;
  int chunk = (N + 255) / 256;
  int lo = t * chunk;
  int hi = lo + chunk; if (hi > N) hi = N;
  int s = 0;
  for (int i = lo; i < hi; ++i) s += counts[i];
  sums[t] = s;
  __syncthreads();
  if (t == 0) {
    int acc = 0;
    for (int i = 0; i < 256; ++i) { offs[i] = acc; acc += sums[i]; }
    indptr[N] = acc;
  }
  __syncthreads();
  int acc = offs[t];
  for (int i = lo; i < hi; ++i) { indptr[i] = acc; acc += counts[i]; }
}

__global__ void fill_kernel(const int* __restrict__ ei, int E, int N,
                            const int* __restrict__ flag,
                            const int* __restrict__ indptr,
                            int* __restrict__ fill, int* __restrict__ csr_src,
                            int* __restrict__ csr_dst) {
  int i = blockIdx.x * blockDim.x + threadIdx.x;
  int total = E + N;
  if (i >= total) return;
  int s, d;
  if (i < E) { int f = *flag; s = eidx(ei, f, i); d = eidx(ei, f, (long long)E + i); }
  else       { s = i - E;  d = s; }
  int p = indptr[d] + atomicAdd(&fill[d], 1);
  csr_src[p] = s;
  csr_dst[p] = d;
}

__global__ void copy_kernel(const float* __restrict__ a, float* __restrict__ b, int n) {
  int i = blockIdx.x * blockDim.x + threadIdx.x;
  if (i < n) b[i] = a[i];
}

// x [N,39] fp32 -> xb [N,64] bf16 zero-padded
__global__ void convert_pad_kernel(const float* __restrict__ x, bf16* __restrict__ xb, int N) {
  int i = blockIdx.x * blockDim.x + threadIdx.x;
  if (i >= N * 64) return;
  int n = i >> 6, c = i & 63;
  float v = (c < 39) ? x[(size_t)n * 39 + c] : 0.f;
  xb[i] = __float2bfloat16(v);
}

// ---------------- MFMA GEMM: Cl (+Cr) (+)= A(bf16) @ W(fp32->bf16) ----------------
// Tile 128(M) x 64(N) x 32(K); 4 waves (2x2). A row-major bf16; W row-major fp32,
// rows >= Kw read as 0. LDS stride 40 bf16 (16B aligned, conflict-light).

template <bool DUAL, bool ACCUM, typename TCL, typename TCR>
__global__ __launch_bounds__(256)
void mfma_gemm_kernel(const bf16* __restrict__ A, int lda, int M, int K, int Kw,
                      const float* __restrict__ Wl, const float* __restrict__ Wr,
                      int ldw,
                      TCL* __restrict__ Cl, int ldcl, TCR* __restrict__ Cr, int ldcr) {
  __shared__ short As[128 * 40];
  __shared__ short Bls[64 * 40];
  __shared__ short Brs[64 * 40];
  int tid = threadIdx.x;
  int lane = tid & 63;
  int wave = tid >> 6;
  int wm = wave >> 1, wn = wave & 1;
  int bm = blockIdx.y * 128, bn = blockIdx.x * 64;
  f32x4 accl[4][2] = {};
  f32x4 accr[4][2] = {};
  int kg = lane >> 4;
  int rr = lane & 15;

  for (int k0 = 0; k0 < K; k0 += 32) {
#pragma unroll
    for (int i = 0; i < 2; ++i) {
      int c = tid + i * 256;
      int r = c >> 2, cg = c & 3;
      int gr = bm + r;
      uint4 u = make_uint4(0u, 0u, 0u, 0u);
      if (gr < M) u = *(const uint4*)(A + (size_t)gr * lda + k0 + cg * 8);
      *(uint4*)(As + r * 40 + cg * 8) = u;
    }
    {
      int c = tid & 63, kb = tid >> 6;
      bf16 pl[8], pr[8];
#pragma unroll
      for (int j = 0; j < 8; ++j) {
        int kk = k0 + kb * 8 + j;
        float vl = 0.f, vr = 0.f;
        if (kk < Kw) {
          size_t w = (size_t)kk * ldw + bn + c;
          vl = Wl[w];
          if (DUAL) vr = Wr[w];
        }
        pl[j] = __float2bfloat16(vl);
        if (DUAL) pr[j] = __float2bfloat16(vr);
      }
      *(uint4*)(Bls + c * 40 + kb * 8) = *(uint4*)pl;
      if (DUAL) *(uint4*)(Brs + c * 40 + kb * 8) = *(uint4*)pr;
    }
    __syncthreads();
    sh8 af[4], blf[2], brf[2];
#pragma unroll
    for (int mi = 0; mi < 4; ++mi)
      af[mi] = *(const sh8*)(As + (wm * 64 + mi * 16 + rr) * 40 + kg * 8);
#pragma unroll
    for (int ni = 0; ni < 2; ++ni) {
      blf[ni] = *(const sh8*)(Bls + (wn * 32 + ni * 16 + rr) * 40 + kg * 8);
      if (DUAL) brf[ni] = *(const sh8*)(Brs + (wn * 32 + ni * 16 + rr) * 40 + kg * 8);
    }
#pragma unroll
    for (int mi = 0; mi < 4; ++mi)
#pragma unroll
      for (int ni = 0; ni < 2; ++ni) {
        accl[mi][ni] = __builtin_amdgcn_mfma_f32_16x16x32_bf16(af[mi], blf[ni], accl[mi][ni], 0, 0, 0);
        if (DUAL)
          accr[mi][ni] = __builtin_amdgcn_mfma_f32_16x16x32_bf16(af[mi], brf[ni], accr[mi][ni], 0, 0, 0);
      }
    __syncthreads();
  }
  int cr0 = (lane >> 4) * 4;  // C/D: col = lane&15, row = (lane>>4)*4 + reg  [m89/m91]
#pragma unroll
  for (int mi = 0; mi < 4; ++mi)
#pragma unroll
    for (int j = 0; j < 4; ++j) {
      int gr = bm + wm * 64 + mi * 16 + cr0 + j;
      if (gr >= M) continue;
#pragma unroll
      for (int ni = 0; ni < 2; ++ni) {
        int gc = bn + wn * 32 + ni * 16 + rr;
        float vl = accl[mi][ni][j];
        size_t ol = (size_t)gr * ldcl + gc;
        if (ACCUM) vl += ldf(&Cl[ol]);
        stf(&Cl[ol], vl);
        if (DUAL) {
          float vr = accr[mi][ni][j];
          size_t orr = (size_t)gr * ldcr + gc;
          if (ACCUM) vr += ldf(&Cr[orr]);
          stf(&Cr[orr], vr);
        }
      }
    }
}

template <bool DUAL, typename TCL, typename TCR>
static void launch_mfma(const bf16* A, int lda, int M, int K, int Kw,
                        const float* Wl, const float* Wr, int ldw, int Fc,
                        TCL* Cl, int ldcl, TCR* Cr, int ldcr, bool accum, hipStream_t st) {
  dim3 grid(Fc / 64, (M + 127) / 128);
  if (accum)
    mfma_gemm_kernel<DUAL, true, TCL, TCR><<<grid, 256, 0, st>>>(A, lda, M, K, Kw, Wl, Wr, ldw, Cl, ldcl, Cr, ldcr);
  else
    mfma_gemm_kernel<DUAL, false, TCL, TCR><<<grid, 256, 0, st>>>(A, lda, M, K, Kw, Wl, Wr, ldw, Cl, ldcl, Cr, ldcr);
}

// ---------------- vector GEMM (fp32; L1 fallback + L5) ----------------

template <typename TA, typename TCL, typename TCR, bool DUAL, bool ACCUM>
__global__ __launch_bounds__(256)
void vgemm_kernel(const TA* __restrict__ A, int lda, int M, int K,
                  const float* __restrict__ Wl, const float* __restrict__ Wr,
                  int ldw, int Fc,
                  TCL* __restrict__ Cl, int ldcl, TCR* __restrict__ Cr, int ldcr) {
  __shared__ float As[BK][BM + 4];
  __shared__ float Bls[BK][BN];
  __shared__ float Brs[BK][BN];
  int tid = threadIdx.x;
  int tx = tid & 15, ty = tid >> 4;
  int bn = blockIdx.x * BN, bm = blockIdx.y * BM;
  float accl[4][4] = {};
  float accr[4][4] = {};
  for (int k0 = 0; k0 < K; k0 += BK) {
#pragma unroll
    for (int i = 0; i < 4; ++i) {
      int idx = tid + i * 256;
      int r = idx >> 4, c = idx & 15;
      int gr = bm + r, gc = k0 + c;
      As[c][r] = (gr < M && gc < K) ? ldf(&A[(size_t)gr * lda + gc]) : 0.f;
    }
#pragma unroll
    for (int i = 0; i < 4; ++i) {
      int idx = tid + i * 256;
      int c = idx >> 6, n = idx & 63;
      int gc = k0 + c, gn = bn + n;
      bool ok = (gc < K && gn < Fc);
      size_t w = (size_t)gc * ldw + gn;
      Bls[c][n] = ok ? Wl[w] : 0.f;
      if (DUAL) Brs[c][n] = ok ? Wr[w] : 0.f;
    }
    __syncthreads();
#pragma unroll
    for (int kk = 0; kk < BK; ++kk) {
      float4 a = *(const float4*)&As[kk][ty * 4];
      float4 bl = *(const float4*)&Bls[kk][tx * 4];
      float av[4] = {a.x, a.y, a.z, a.w};
      float blv[4] = {bl.x, bl.y, bl.z, bl.w};
      float brv[4] = {0.f, 0.f, 0.f, 0.f};
      if (DUAL) {
        float4 br = *(const float4*)&Brs[kk][tx * 4];
        brv[0] = br.x; brv[1] = br.y; brv[2] = br.z; brv[3] = br.w;
      }
#pragma unroll
      for (int i = 0; i < 4; ++i)
#pragma unroll
        for (int j = 0; j < 4; ++j) {
          accl[i][j] += av[i] * blv[j];
          if (DUAL) accr[i][j] += av[i] * brv[j];
        }
    }
    __syncthreads();
  }
#pragma unroll
  for (int i = 0; i < 4; ++i) {
    int gr = bm + ty * 4 + i;
    if (gr >= M) continue;
#pragma unroll
    for (int j = 0; j < 4; ++j) {
      int gn = bn + tx * 4 + j;
      if (gn >= Fc) continue;
      float vl = accl[i][j];
      size_t ol = (size_t)gr * ldcl + gn;
      if (ACCUM) vl += ldf(&Cl[ol]);
      stf(&Cl[ol], vl);
      if (DUAL) {
        float vr = accr[i][j];
        size_t orr = (size_t)gr * ldcr + gn;
        if (ACCUM) vr += ldf(&Cr[orr]);
        stf(&Cr[orr], vr);
      }
    }
  }
}

template <typename TA, typename TCL, typename TCR>
static void launch_vgemm(const TA* A, int lda, int M, int K,
                         const float* Wl, const float* Wr, int ldw, int Fc,
                         TCL* Cl, int ldcl, TCR* Cr, int ldcr, bool accum, hipStream_t st) {
  dim3 grid((Fc + BN - 1) / BN, (M + BM - 1) / BM);
  if (Wr) {
    if (accum) vgemm_kernel<TA, TCL, TCR, true, true><<<grid, 256, 0, st>>>(A, lda, M, K, Wl, Wr, ldw, Fc, Cl, ldcl, Cr, ldcr);
    else       vgemm_kernel<TA, TCL, TCR, true, false><<<grid, 256, 0, st>>>(A, lda, M, K, Wl, Wr, ldw, Fc, Cl, ldcl, Cr, ldcr);
  } else {
    if (accum) vgemm_kernel<TA, TCL, TCR, false, true><<<grid, 256, 0, st>>>(A, lda, M, K, Wl, Wl, ldw, Fc, Cl, ldcl, Cr, ldcr);
    else       vgemm_kernel<TA, TCL, TCR, false, false><<<grid, 256, 0, st>>>(A, lda, M, K, Wl, Wl, ldw, Fc, Cl, ldcl, Cr, ldcr);
  }
}

// ---------------- edge scores ----------------

template <typename TSL, typename TSR, bool ACCUM>
__global__ void edge_e_kernel(const TSL* __restrict__ xl, int ldxl,
                              const TSR* __restrict__ xr, int ldxr,
                              const int* __restrict__ csr_src, const int* __restrict__ csr_dst,
                              const float* __restrict__ att, float* __restrict__ ev,
                              int Etot, int Fc) {
  int gid = blockIdx.x * blockDim.x + threadIdx.x;
  int edge = gid >> 6;
  int lane = threadIdx.x & 63;
  if (edge >= Etot) return;
  int s = csr_src[edge], d = csr_dst[edge];
  const TSL* pl = xl + (size_t)s * ldxl;
  const TSR* pr = xr + (size_t)d * ldxr;
  float acc = 0.f;
  for (int f = lane; f < Fc; f += 64) {
    float h = ldf(&pl[f]) + ldf(&pr[f]);
    h = h > 0.f ? h : NEG_SLOPE * h;
    acc += h * att[f];
  }
#pragma unroll
  for (int off = 32; off > 0; off >>= 1) acc += __shfl_down(acc, off);
  if (lane == 0) {
    if (ACCUM) ev[edge] += acc;
    else ev[edge] = acc;
  }
}

template <typename TSL, typename TSR>
static void launch_edge(const TSL* xl, int ldxl, const TSR* xr, int ldxr,
                        const int* cs, const int* cd,
                        const float* att, float* ev, int Etot, int Fc, bool accum,
                        hipStream_t st) {
  int blocks = (int)(((long long)Etot * 64 + 255) / 256);
  if (accum) edge_e_kernel<TSL, TSR, true><<<blocks, 256, 0, st>>>(xl, ldxl, xr, ldxr, cs, cd, att, ev, Etot, Fc);
  else       edge_e_kernel<TSL, TSR, false><<<blocks, 256, 0, st>>>(xl, ldxl, xr, ldxr, cs, cd, att, ev, Etot, Fc);
}

template <typename TSL, typename TSR, bool ACCUM>
__global__ void edge_vec_kernel(const TSL* __restrict__ xl, int ldxl,
                                const TSR* __restrict__ xr, int ldxr,
                                const int* __restrict__ csr_src, const int* __restrict__ csr_dst,
                                const float* __restrict__ att, float* __restrict__ ev,
                                int Etot, int Fc) {
  int gid = blockIdx.x * blockDim.x + threadIdx.x;
  int edge = gid >> 6;
  int lane = threadIdx.x & 63;
  if (edge >= Etot) return;
  int s = csr_src[edge], d = csr_dst[edge];
  const TSL* pl = xl + (size_t)s * ldxl;
  const TSR* pr = xr + (size_t)d * ldxr;
  float acc = 0.f;
  for (int f = 2 * lane; f < Fc; f += 128) {
    float2 l = ld2f(pl + f);
    float2 r = ld2f(pr + f);
    float2 at = *(const float2*)(att + f);
    float h0 = l.x + r.x; h0 = h0 > 0.f ? h0 : NEG_SLOPE * h0;
    float h1 = l.y + r.y; h1 = h1 > 0.f ? h1 : NEG_SLOPE * h1;
    acc += h0 * at.x + h1 * at.y;
  }
#pragma unroll
  for (int off = 32; off > 0; off >>= 1) acc += __shfl_down(acc, off);
  if (lane == 0) {
    if (ACCUM) ev[edge] += acc;
    else ev[edge] = acc;
  }
}

template <typename TSL, typename TSR>
static void launch_edge_vec(const TSL* xl, int ldxl, const TSR* xr, int ldxr,
                            const int* cs, const int* cd,
                            const float* att, float* ev, int Etot, int Fc, bool accum,
                            hipStream_t st) {
  int blocks = (int)(((long long)Etot * 64 + 255) / 256);
  if (accum) edge_vec_kernel<TSL, TSR, true><<<blocks, 256, 0, st>>>(xl, ldxl, xr, ldxr, cs, cd, att, ev, Etot, Fc);
  else       edge_vec_kernel<TSL, TSR, false><<<blocks, 256, 0, st>>>(xl, ldxl, xr, ldxr, cs, cd, att, ev, Etot, Fc);
}

// ---------------- segment softmax ----------------

__global__ void softmax_kernel(float* __restrict__ ev, const int* __restrict__ indptr, int N) {
  int i = blockIdx.x * blockDim.x + threadIdx.x;
  if (i >= N) return;
  int lo = indptr[i], hi = indptr[i + 1];
  float m = -1e30f;
  for (int j = lo; j < hi; ++j) m = fmaxf(m, ev[j]);
  float s = 0.f;
  for (int j = lo; j < hi; ++j) { float x = expf(ev[j] - m); ev[j] = x; s += x; }
  float inv = 1.f / s;
  for (int j = lo; j < hi; ++j) ev[j] *= inv;
}

// ---------------- aggregation (vectorized; Fc = NP*128) ----------------

template <int NP, typename TS, typename TD>
__global__ void agg_vec_kernel(const TS* __restrict__ xl, int ldx,
                               const float* __restrict__ alpha,
                               const int* __restrict__ csr_src, const int* __restrict__ indptr,
                               const float* __restrict__ bias,
                               TD* __restrict__ out, int ldout, int N, int relu) {
  int gid = blockIdx.x * blockDim.x + threadIdx.x;
  int node = gid >> 6;
  int lane = threadIdx.x & 63;
  if (node >= N) return;
  float ax[NP], ay[NP];
#pragma unroll
  for (int p = 0; p < NP; ++p) {
    float2 b = *(const float2*)(bias + 2 * lane + p * 128);
    ax[p] = b.x; ay[p] = b.y;
  }
  int lo = indptr[node], hi = indptr[node + 1];
  for (int j = lo; j < hi; ++j) {
    float a = alpha[j];
    const TS* row = xl + (size_t)csr_src[j] * ldx;
#pragma unroll
    for (int p = 0; p < NP; ++p) {
      float2 v = ld2f(row + 2 * lane + p * 128);
      ax[p] += a * v.x;
      ay[p] += a * v.y;
    }
  }
#pragma unroll
  for (int p = 0; p < NP; ++p) {
    float vx = ax[p], vy = ay[p];
    if (relu) { vx = fmaxf(vx, 0.f); vy = fmaxf(vy, 0.f); }
    st2f(&out[(size_t)node * ldout + 2 * lane + p * 128], vx, vy);
  }
}

template <typename TS, typename TD>
static void launch_agg_vec(const TS* xl, int ldx, const float* alpha, const int* cs, const int* ip,
                           const float* bias, TD* out, int ldout, int N, int Fc, int relu,
                           hipStream_t st) {
  int blocks = (int)(((long long)N * 64 + 255) / 256);
  switch (Fc >> 7) {
    case 4: agg_vec_kernel<4, TS, TD><<<blocks, 256, 0, st>>>(xl, ldx, alpha, cs, ip, bias, out, ldout, N, relu); break;
    case 2: agg_vec_kernel<2, TS, TD><<<blocks, 256, 0, st>>>(xl, ldx, alpha, cs, ip, bias, out, ldout, N, relu); break;
    case 1: agg_vec_kernel<1, TS, TD><<<blocks, 256, 0, st>>>(xl, ldx, alpha, cs, ip, bias, out, ldout, N, relu); break;
  }
}

__global__ void aggregate3_kernel(const float* __restrict__ xl, const float* __restrict__ alpha,
                                  const int* __restrict__ csr_src, const int* __restrict__ indptr,
                                  const float* __restrict__ bias, float* __restrict__ out, int N) {
  int i = blockIdx.x * blockDim.x + threadIdx.x;
  if (i >= N) return;
  float a0 = bias[0], a1 = bias[1], a2 = bias[2];
  int lo = indptr[i], hi = indptr[i + 1];
  for (int j = lo; j < hi; ++j) {
    float a = alpha[j];
    const float* row = xl + (size_t)csr_src[j] * 3;
    a0 += a * row[0];
    a1 += a * row[1];
    a2 += a * row[2];
  }
  out[(size_t)i * 3 + 0] = a0;
  out[(size_t)i * 3 + 1] = a1;
  out[(size_t)i * 3 + 2] = a2;
}

// ---------------- launch ----------------

extern "C" void kernel_launch(void* const* d_in, const int* in_sizes, int n_in,
                              void* d_out, int out_size, void* d_ws, size_t ws_size,
                              hipStream_t stream) {
  const float* x = (const float*)d_in[0];
  const int* ei = (const int*)d_in[1];
  const int N = in_sizes[0] / 39;
  const int E = in_sizes[1] / 2;
  const int Etot = E + N;
  (void)n_in; (void)out_size;

  const float* Wl[5]; const float* Wr[5]; const float* att[5]; const float* bb[5];
  for (int l = 0; l < 5; ++l) {
    Wl[l]  = (const float*)d_in[2 + 4 * l];
    Wr[l]  = (const float*)d_in[3 + 4 * l];
    att[l] = (const float*)d_in[4 + 4 * l];
    bb[l]  = (const float*)d_in[5 + 4 * l];
  }

  char* ws = (char*)d_ws;
  size_t off = 0;
  auto alloc = [&](size_t b) -> char* {
    char* p = ws + off;
    off += (b + 255) & ~(size_t)255;
    return p;
  };
  int* counts  = (int*)alloc((size_t)N * 4);
  int* fillc   = (int*)alloc((size_t)N * 4);
  int* flag    = (int*)alloc(256);
  int* indptr  = (int*)alloc(((size_t)N + 1) * 4);
  int* csr_s   = (int*)alloc((size_t)Etot * 4);
  int* csr_d   = (int*)alloc((size_t)Etot * 4);
  float* ev    = (float*)alloc((size_t)Etot * 4);
  float* alpha1 = (float*)alloc((size_t)Etot * 4);

  // regions (slim layout, proven to fit: ws >= ~217 MB)
  char* R0 = alloc((size_t)N * 256);   // xl1c [N,128]bf16 | XR3 low | out3 low
  char* R1 = alloc((size_t)N * 256);   // t1   [N,128]bf16 | XR3 high | out3 high
  char* R2 = alloc((size_t)N * 512);   // waccL fp32 [N,128] | XL3 | XL4+XR4
  char* R3 = alloc((size_t)N * 512);   // waccR fp32 | out2 low | XL5,XR5
  char* R4 = alloc((size_t)N * 512);   // out2 high
  (void)R4;
  size_t base_need = off + 4096;
  if (ws_size < base_need) return;

  // optional +12.8MB tier: bf16-padded x enables MFMA for layer-1 GEMMs
  bool use_xpad = (ws_size >= base_need + (size_t)N * 128 + 256);
  bf16* xpad = use_xpad ? (bf16*)alloc((size_t)N * 128) : nullptr;

  const int tb = 256;
  init_counts_kernel<<<(N + tb - 1) / tb, tb, 0, stream>>>(counts, fillc, N, flag);
  detect_kernel<<<(E + tb - 1) / tb, tb, 0, stream>>>(ei, E, flag);
  count_kernel<<<(E + tb - 1) / tb, tb, 0, stream>>>(ei, E, flag, counts);
  scan_kernel<<<1, 256, 0, stream>>>(counts, indptr, N);
  fill_kernel<<<(Etot + tb - 1) / tb, tb, 0, stream>>>(ei, E, N, flag, indptr,
                                                       fillc, csr_s, csr_d);

  bf16* xl1c = (bf16*)R0;
  bf16* t1   = (bf16*)R1;
  float* waccL = (float*)R2;
  float* waccR = (float*)R3;
  bf16* out2 = (bf16*)R3;  // spans R3+R4

  if (use_xpad)
    convert_pad_kernel<<<(N * 64 + tb - 1) / tb, tb, 0, stream>>>(x, xpad, N);

  // ---- Layer 1 (39 -> 1024): alpha1 only; out1 virtual ----
  for (int kc = 0; kc < 8; ++kc) {
    if (use_xpad)
      launch_mfma<true, bf16, bf16>(xpad, 64, N, 64, 39, Wl[0] + kc * 128, Wr[0] + kc * 128,
                                    1024, 128, xl1c, 128, t1, 128, false, stream);
    else
      launch_vgemm<float, bf16, bf16>(x, 39, N, 39, Wl[0] + kc * 128, Wr[0] + kc * 128, 1024, 128,
                                      xl1c, 128, t1, 128, false, stream);
    launch_edge_vec<bf16, bf16>(xl1c, 128, t1, 128, csr_s, csr_d, att[0] + kc * 128,
                                ev, Etot, 128, kc > 0, stream);
  }
  softmax_kernel<<<(N + tb - 1) / tb, tb, 0, stream>>>(ev, indptr, N);
  copy_kernel<<<(Etot + tb - 1) / tb, tb, 0, stream>>>(ev, alpha1, Etot);

  auto mat_out1 = [&](int kc) {
    if (use_xpad)
      launch_mfma<false, bf16, bf16>(xpad, 64, N, 64, 39, Wl[0] + kc * 128, Wl[0] + kc * 128,
                                     1024, 128, xl1c, 128, xl1c, 128, false, stream);
    else
      launch_vgemm<float, bf16, bf16>(x, 39, N, 39, Wl[0] + kc * 128, nullptr, 1024, 128,
                                      xl1c, 128, xl1c, 128, false, stream);
    launch_agg_vec<bf16, bf16>(xl1c, 128, alpha1, csr_s, indptr, bb[0] + kc * 128,
                               t1, 128, N, 128, 1, stream);
  };

  // ---- Layer 2 (1024 -> 512), virtual out1, fc-chunked, MFMA ----
  for (int fc = 0; fc < 4; ++fc) {
    for (int kc = 0; kc < 8; ++kc) {
      mat_out1(kc);
      const float* wl = Wl[1] + (size_t)kc * 128 * 512 + fc * 128;
      const float* wr = Wr[1] + (size_t)kc * 128 * 512 + fc * 128;
      launch_mfma<true, float, float>(t1, 128, N, 128, 128, wl, wr, 512, 128,
                                      waccL, 128, waccR, 128, kc > 0, stream);
    }
    launch_edge_vec<float, float>(waccL, 128, waccR, 128, csr_s, csr_d,
                                  att[1] + fc * 128, ev, Etot, 128, fc > 0, stream);
  }
  softmax_kernel<<<(N + tb - 1) / tb, tb, 0, stream>>>(ev, indptr, N);
  for (int i = 0; i < 4; ++i) {
    int fc = (i == 0) ? 3 : (i - 1);   // fc=3 first: waccL still holds its XL chunk
    if (i > 0) {
      for (int kc = 0; kc < 8; ++kc) {
        mat_out1(kc);
        const float* wl = Wl[1] + (size_t)kc * 128 * 512 + fc * 128;
        launch_mfma<false, float, float>(t1, 128, N, 128, 128, wl, wl, 512, 128,
                                         waccL, 128, waccL, 128, kc > 0, stream);
      }
    }
    launch_agg_vec<float, bf16>(waccL, 128, ev, csr_s, indptr, bb[1] + fc * 128,
                                out2 + fc * 128, 512, N, 128, 1, stream);
  }

  // ---- Layer 3 (512 -> 256), MFMA ----
  bf16* XL3 = (bf16*)R2;
  bf16* XR3 = (bf16*)R0;  // spans R0+R1
  launch_mfma<true, bf16, bf16>(out2, 512, N, 512, 512, Wl[2], Wr[2], 256, 256,
                                XL3, 256, XR3, 256, false, stream);
  launch_edge_vec<bf16, bf16>(XL3, 256, XR3, 256, csr_s, csr_d, att[2], ev, Etot, 256, false, stream);
  softmax_kernel<<<(N + tb - 1) / tb, tb, 0, stream>>>(ev, indptr, N);
  bf16* out3 = XR3;
  launch_agg_vec<bf16, bf16>(XL3, 256, ev, csr_s, indptr, bb[2], out3, 256, N, 256, 1, stream);

  // ---- Layer 4 (256 -> 128), MFMA -> d_out fp32 ----
  bf16* XL4 = (bf16*)R2;
  bf16* XR4 = (bf16*)(R2 + (size_t)N * 256);
  launch_mfma<true, bf16, bf16>(out3, 256, N, 256, 256, Wl[3], Wr[3], 128, 128,
                                XL4, 128, XR4, 128, false, stream);
  launch_edge_vec<bf16, bf16>(XL4, 128, XR4, 128, csr_s, csr_d, att[3], ev, Etot, 128, false, stream);
  softmax_kernel<<<(N + tb - 1) / tb, tb, 0, stream>>>(ev, indptr, N);
  launch_agg_vec<bf16, float>(XL4, 128, ev, csr_s, indptr, bb[3], (float*)d_out, 128, N, 128, 1, stream);

  // ---- Layer 5 (128 -> 3) -> coords fp32 ----
  float* XL5 = (float*)R3;
  float* XR5 = (float*)(R3 + (((size_t)N * 12 + 255) & ~(size_t)255));
  launch_vgemm<float, float, float>((const float*)d_out, 128, N, 128, Wl[4], Wr[4], 3, 3,
                                    XL5, 3, XR5, 3, false, stream);
  launch_edge<float, float>(XL5, 3, XR5, 3, csr_s, csr_d, att[4], ev, Etot, 3, false, stream);
  softmax_kernel<<<(N + tb - 1) / tb, tb, 0, stream>>>(ev, indptr, N);
  aggregate3_kernel<<<(N + tb - 1) / tb, tb, 0, stream>>>(XL5, ev, csr_s, indptr, bb[4],
                                                          (float*)d_out + (size_t)N * 128, N);
}

// Round 11
// 10286.281 us; speedup vs baseline: 2.3691x; 1.2127x over previous
//
#include <hip/hip_runtime.h>
#include <hip/hip_bf16.h>
#include <math.h>

#define NEG_SLOPE 0.2f
#define BM 64
#define BN 64
#define BK 16

typedef __hip_bfloat16 bf16;
typedef __attribute__((ext_vector_type(8))) short sh8;
typedef __attribute__((ext_vector_type(4))) float f32x4;

__device__ __forceinline__ float ldf(const float* p) { return *p; }
__device__ __forceinline__ float ldf(const bf16* p) { return __bfloat162float(*p); }
__device__ __forceinline__ void stf(float* p, float v) { *p = v; }
__device__ __forceinline__ void stf(bf16* p, float v) { *p = __float2bfloat16(v); }

__device__ __forceinline__ float2 ld2f(const bf16* p) {
  unsigned int u = *(const unsigned int*)p;
  float2 r;
  r.x = __uint_as_float((u & 0xffffu) << 16);
  r.y = __uint_as_float(u & 0xffff0000u);
  return r;
}
__device__ __forceinline__ float2 ld2f(const float* p) { return *(const float2*)p; }
__device__ __forceinline__ void st2f(bf16* p, float a, float b) {
  bf16 t[2] = { __float2bfloat16(a), __float2bfloat16(b) };
  *(unsigned int*)p = *(unsigned int*)t;
}
__device__ __forceinline__ void st2f(float* p, float a, float b) {
  float2 v; v.x = a; v.y = b; *(float2*)p = v;
}

__device__ __forceinline__ int eidx(const int* __restrict__ ei, int f64, long long j) {
  return f64 ? ei[2 * j] : ei[(size_t)j];
}

// ---------------- dtype detect + CSR build ----------------

__global__ void init_counts_kernel(int* counts, int* fill, int N, int* flag) {
  int i = blockIdx.x * blockDim.x + threadIdx.x;
  if (i < N) { counts[i] = 1; fill[i] = 0; }
  if (i == 0) *flag = 1;
}

__global__ void detect_kernel(const int* __restrict__ ei, int E, int* flag) {
  int i = blockIdx.x * blockDim.x + threadIdx.x;
  bool nz = (i < E) && (ei[2 * i + 1] != 0);
  if (__any(nz) && (threadIdx.x & 63) == 0) atomicAnd(flag, 0);
}

__global__ void count_kernel(const int* __restrict__ ei, int E,
                             const int* __restrict__ flag, int* __restrict__ counts) {
  int i = blockIdx.x * blockDim.x + threadIdx.x;
  if (i < E) {
    int d = eidx(ei, *flag, (long long)E + i);
    atomicAdd(&counts[d], 1);
  }
}

__global__ void scan_kernel(const int* __restrict__ counts, int* __restrict__ indptr, int N) {
  __shared__ int sums[256];
  __shared__ int offs[256];
  int t = threadIdx.x;
  int chunk = (N + 255) / 256;
  int lo = t * chunk;
  int hi = lo + chunk; if (hi > N) hi = N;
  int s = 0;
  for (int i = lo; i < hi; ++i) s += counts[i];
  sums[t] = s;
  __syncthreads();
  if (t == 0) {
    int acc = 0;
    for (int i = 0; i < 256; ++i) { offs[i] = acc; acc += sums[i]; }
    indptr[N] = acc;
  }
  __syncthreads();
  int acc = offs[t];
  for (int i = lo; i < hi; ++i) { indptr[i] = acc; acc += counts[i]; }
}

__global__ void fill_kernel(const int* __restrict__ ei, int E, int N,
                            const int* __restrict__ flag,
                            const int* __restrict__ indptr,
                            int* __restrict__ fill, int* __restrict__ csr_src,
                            int* __restrict__ csr_dst) {
  int i = blockIdx.x * blockDim.x + threadIdx.x;
  int total = E + N;
  if (i >= total) return;
  int s, d;
  if (i < E) { int f = *flag; s = eidx(ei, f, i); d = eidx(ei, f, (long long)E + i); }
  else       { s = i - E;  d = s; }
  int p = indptr[d] + atomicAdd(&fill[d], 1);
  csr_src[p] = s;
  csr_dst[p] = d;
}

__global__ void copy_kernel(const float* __restrict__ a, float* __restrict__ b, int n) {
  int i = blockIdx.x * blockDim.x + threadIdx.x;
  if (i < n) b[i] = a[i];
}

// fp32 -> bf16 pairwise convert (n even)
__global__ void f2b_kernel(const float* __restrict__ src, bf16* __restrict__ dst, int npair) {
  int i = blockIdx.x * blockDim.x + threadIdx.x;
  if (i >= npair) return;
  float2 v = *(const float2*)(src + 2 * i);
  st2f(dst + 2 * i, v.x, v.y);
}

// x [N,39] fp32 -> xb [N,64] bf16 zero-padded
__global__ void convert_pad_kernel(const float* __restrict__ x, bf16* __restrict__ xb, int N) {
  int i = blockIdx.x * blockDim.x + threadIdx.x;
  if (i >= N * 64) return;
  int n = i >> 6, c = i & 63;
  float v = (c < 39) ? x[(size_t)n * 39 + c] : 0.f;
  xb[i] = __float2bfloat16(v);
}

// ---------------- MFMA GEMM: Cl (+Cr) (+)= A(bf16) @ W(fp32->bf16) ----------------

template <bool DUAL, bool ACCUM, typename TCL, typename TCR>
__global__ __launch_bounds__(256)
void mfma_gemm_kernel(const bf16* __restrict__ A, int lda, int M, int K, int Kw,
                      const float* __restrict__ Wl, const float* __restrict__ Wr,
                      int ldw,
                      TCL* __restrict__ Cl, int ldcl, TCR* __restrict__ Cr, int ldcr) {
  __shared__ short As[128 * 40];
  __shared__ short Bls[64 * 40];
  __shared__ short Brs[64 * 40];
  int tid = threadIdx.x;
  int lane = tid & 63;
  int wave = tid >> 6;
  int wm = wave >> 1, wn = wave & 1;
  int bm = blockIdx.y * 128, bn = blockIdx.x * 64;
  f32x4 accl[4][2] = {};
  f32x4 accr[4][2] = {};
  int kg = lane >> 4;
  int rr = lane & 15;

  for (int k0 = 0; k0 < K; k0 += 32) {
#pragma unroll
    for (int i = 0; i < 2; ++i) {
      int c = tid + i * 256;
      int r = c >> 2, cg = c & 3;
      int gr = bm + r;
      uint4 u = make_uint4(0u, 0u, 0u, 0u);
      if (gr < M) u = *(const uint4*)(A + (size_t)gr * lda + k0 + cg * 8);
      *(uint4*)(As + r * 40 + cg * 8) = u;
    }
    {
      int c = tid & 63, kb = tid >> 6;
      bf16 pl[8], pr[8];
#pragma unroll
      for (int j = 0; j < 8; ++j) {
        int kk = k0 + kb * 8 + j;
        float vl = 0.f, vr = 0.f;
        if (kk < Kw) {
          size_t w = (size_t)kk * ldw + bn + c;
          vl = Wl[w];
          if (DUAL) vr = Wr[w];
        }
        pl[j] = __float2bfloat16(vl);
        if (DUAL) pr[j] = __float2bfloat16(vr);
      }
      *(uint4*)(Bls + c * 40 + kb * 8) = *(uint4*)pl;
      if (DUAL) *(uint4*)(Brs + c * 40 + kb * 8) = *(uint4*)pr;
    }
    __syncthreads();
    sh8 af[4], blf[2], brf[2];
#pragma unroll
    for (int mi = 0; mi < 4; ++mi)
      af[mi] = *(const sh8*)(As + (wm * 64 + mi * 16 + rr) * 40 + kg * 8);
#pragma unroll
    for (int ni = 0; ni < 2; ++ni) {
      blf[ni] = *(const sh8*)(Bls + (wn * 32 + ni * 16 + rr) * 40 + kg * 8);
      if (DUAL) brf[ni] = *(const sh8*)(Brs + (wn * 32 + ni * 16 + rr) * 40 + kg * 8);
    }
#pragma unroll
    for (int mi = 0; mi < 4; ++mi)
#pragma unroll
      for (int ni = 0; ni < 2; ++ni) {
        accl[mi][ni] = __builtin_amdgcn_mfma_f32_16x16x32_bf16(af[mi], blf[ni], accl[mi][ni], 0, 0, 0);
        if (DUAL)
          accr[mi][ni] = __builtin_amdgcn_mfma_f32_16x16x32_bf16(af[mi], brf[ni], accr[mi][ni], 0, 0, 0);
      }
    __syncthreads();
  }
  int cr0 = (lane >> 4) * 4;  // C/D: col = lane&15, row = (lane>>4)*4 + reg
#pragma unroll
  for (int mi = 0; mi < 4; ++mi)
#pragma unroll
    for (int j = 0; j < 4; ++j) {
      int gr = bm + wm * 64 + mi * 16 + cr0 + j;
      if (gr >= M) continue;
#pragma unroll
      for (int ni = 0; ni < 2; ++ni) {
        int gc = bn + wn * 32 + ni * 16 + rr;
        float vl = accl[mi][ni][j];
        size_t ol = (size_t)gr * ldcl + gc;
        if (ACCUM) vl += ldf(&Cl[ol]);
        stf(&Cl[ol], vl);
        if (DUAL) {
          float vr = accr[mi][ni][j];
          size_t orr = (size_t)gr * ldcr + gc;
          if (ACCUM) vr += ldf(&Cr[orr]);
          stf(&Cr[orr], vr);
        }
      }
    }
}

template <bool DUAL, typename TCL, typename TCR>
static void launch_mfma(const bf16* A, int lda, int M, int K, int Kw,
                        const float* Wl, const float* Wr, int ldw, int Fc,
                        TCL* Cl, int ldcl, TCR* Cr, int ldcr, bool accum, hipStream_t st) {
  dim3 grid(Fc / 64, (M + 127) / 128);
  if (accum)
    mfma_gemm_kernel<DUAL, true, TCL, TCR><<<grid, 256, 0, st>>>(A, lda, M, K, Kw, Wl, Wr, ldw, Cl, ldcl, Cr, ldcr);
  else
    mfma_gemm_kernel<DUAL, false, TCL, TCR><<<grid, 256, 0, st>>>(A, lda, M, K, Kw, Wl, Wr, ldw, Cl, ldcl, Cr, ldcr);
}

// ---------------- vector GEMM (fp32; L1 fallback + L5) ----------------

template <typename TA, typename TCL, typename TCR, bool DUAL, bool ACCUM>
__global__ __launch_bounds__(256)
void vgemm_kernel(const TA* __restrict__ A, int lda, int M, int K,
                  const float* __restrict__ Wl, const float* __restrict__ Wr,
                  int ldw, int Fc,
                  TCL* __restrict__ Cl, int ldcl, TCR* __restrict__ Cr, int ldcr) {
  __shared__ float As[BK][BM + 4];
  __shared__ float Bls[BK][BN];
  __shared__ float Brs[BK][BN];
  int tid = threadIdx.x;
  int tx = tid & 15, ty = tid >> 4;
  int bn = blockIdx.x * BN, bm = blockIdx.y * BM;
  float accl[4][4] = {};
  float accr[4][4] = {};
  for (int k0 = 0; k0 < K; k0 += BK) {
#pragma unroll
    for (int i = 0; i < 4; ++i) {
      int idx = tid + i * 256;
      int r = idx >> 4, c = idx & 15;
      int gr = bm + r, gc = k0 + c;
      As[c][r] = (gr < M && gc < K) ? ldf(&A[(size_t)gr * lda + gc]) : 0.f;
    }
#pragma unroll
    for (int i = 0; i < 4; ++i) {
      int idx = tid + i * 256;
      int c = idx >> 6, n = idx & 63;
      int gc = k0 + c, gn = bn + n;
      bool ok = (gc < K && gn < Fc);
      size_t w = (size_t)gc * ldw + gn;
      Bls[c][n] = ok ? Wl[w] : 0.f;
      if (DUAL) Brs[c][n] = ok ? Wr[w] : 0.f;
    }
    __syncthreads();
#pragma unroll
    for (int kk = 0; kk < BK; ++kk) {
      float4 a = *(const float4*)&As[kk][ty * 4];
      float4 bl = *(const float4*)&Bls[kk][tx * 4];
      float av[4] = {a.x, a.y, a.z, a.w};
      float blv[4] = {bl.x, bl.y, bl.z, bl.w};
      float brv[4] = {0.f, 0.f, 0.f, 0.f};
      if (DUAL) {
        float4 br = *(const float4*)&Brs[kk][tx * 4];
        brv[0] = br.x; brv[1] = br.y; brv[2] = br.z; brv[3] = br.w;
      }
#pragma unroll
      for (int i = 0; i < 4; ++i)
#pragma unroll
        for (int j = 0; j < 4; ++j) {
          accl[i][j] += av[i] * blv[j];
          if (DUAL) accr[i][j] += av[i] * brv[j];
        }
    }
    __syncthreads();
  }
#pragma unroll
  for (int i = 0; i < 4; ++i) {
    int gr = bm + ty * 4 + i;
    if (gr >= M) continue;
#pragma unroll
    for (int j = 0; j < 4; ++j) {
      int gn = bn + tx * 4 + j;
      if (gn >= Fc) continue;
      float vl = accl[i][j];
      size_t ol = (size_t)gr * ldcl + gn;
      if (ACCUM) vl += ldf(&Cl[ol]);
      stf(&Cl[ol], vl);
      if (DUAL) {
        float vr = accr[i][j];
        size_t orr = (size_t)gr * ldcr + gn;
        if (ACCUM) vr += ldf(&Cr[orr]);
        stf(&Cr[orr], vr);
      }
    }
  }
}

template <typename TA, typename TCL, typename TCR>
static void launch_vgemm(const TA* A, int lda, int M, int K,
                         const float* Wl, const float* Wr, int ldw, int Fc,
                         TCL* Cl, int ldcl, TCR* Cr, int ldcr, bool accum, hipStream_t st) {
  dim3 grid((Fc + BN - 1) / BN, (M + BM - 1) / BM);
  if (Wr) {
    if (accum) vgemm_kernel<TA, TCL, TCR, true, true><<<grid, 256, 0, st>>>(A, lda, M, K, Wl, Wr, ldw, Fc, Cl, ldcl, Cr, ldcr);
    else       vgemm_kernel<TA, TCL, TCR, true, false><<<grid, 256, 0, st>>>(A, lda, M, K, Wl, Wr, ldw, Fc, Cl, ldcl, Cr, ldcr);
  } else {
    if (accum) vgemm_kernel<TA, TCL, TCR, false, true><<<grid, 256, 0, st>>>(A, lda, M, K, Wl, Wl, ldw, Fc, Cl, ldcl, Cr, ldcr);
    else       vgemm_kernel<TA, TCL, TCR, false, false><<<grid, 256, 0, st>>>(A, lda, M, K, Wl, Wl, ldw, Fc, Cl, ldcl, Cr, ldcr);
  }
}

// ---------------- edge scores ----------------

template <typename TSL, typename TSR, bool ACCUM>
__global__ void edge_e_kernel(const TSL* __restrict__ xl, int ldxl,
                              const TSR* __restrict__ xr, int ldxr,
                              const int* __restrict__ csr_src, const int* __restrict__ csr_dst,
                              const float* __restrict__ att, float* __restrict__ ev,
                              int Etot, int Fc) {
  int gid = blockIdx.x * blockDim.x + threadIdx.x;
  int edge = gid >> 6;
  int lane = threadIdx.x & 63;
  if (edge >= Etot) return;
  int s = csr_src[edge], d = csr_dst[edge];
  const TSL* pl = xl + (size_t)s * ldxl;
  const TSR* pr = xr + (size_t)d * ldxr;
  float acc = 0.f;
  for (int f = lane; f < Fc; f += 64) {
    float h = ldf(&pl[f]) + ldf(&pr[f]);
    h = h > 0.f ? h : NEG_SLOPE * h;
    acc += h * att[f];
  }
#pragma unroll
  for (int off = 32; off > 0; off >>= 1) acc += __shfl_down(acc, off);
  if (lane == 0) {
    if (ACCUM) ev[edge] += acc;
    else ev[edge] = acc;
  }
}

template <typename TSL, typename TSR>
static void launch_edge(const TSL* xl, int ldxl, const TSR* xr, int ldxr,
                        const int* cs, const int* cd,
                        const float* att, float* ev, int Etot, int Fc, bool accum,
                        hipStream_t st) {
  int blocks = (int)(((long long)Etot * 64 + 255) / 256);
  if (accum) edge_e_kernel<TSL, TSR, true><<<blocks, 256, 0, st>>>(xl, ldxl, xr, ldxr, cs, cd, att, ev, Etot, Fc);
  else       edge_e_kernel<TSL, TSR, false><<<blocks, 256, 0, st>>>(xl, ldxl, xr, ldxr, cs, cd, att, ev, Etot, Fc);
}

template <typename TSL, typename TSR, bool ACCUM>
__global__ void edge_vec_kernel(const TSL* __restrict__ xl, int ldxl,
                                const TSR* __restrict__ xr, int ldxr,
                                const int* __restrict__ csr_src, const int* __restrict__ csr_dst,
                                const float* __restrict__ att, float* __restrict__ ev,
                                int Etot, int Fc) {
  int gid = blockIdx.x * blockDim.x + threadIdx.x;
  int edge = gid >> 6;
  int lane = threadIdx.x & 63;
  if (edge >= Etot) return;
  int s = csr_src[edge], d = csr_dst[edge];
  const TSL* pl = xl + (size_t)s * ldxl;
  const TSR* pr = xr + (size_t)d * ldxr;
  float acc = 0.f;
  for (int f = 2 * lane; f < Fc; f += 128) {
    float2 l = ld2f(pl + f);
    float2 r = ld2f(pr + f);
    float2 at = *(const float2*)(att + f);
    float h0 = l.x + r.x; h0 = h0 > 0.f ? h0 : NEG_SLOPE * h0;
    float h1 = l.y + r.y; h1 = h1 > 0.f ? h1 : NEG_SLOPE * h1;
    acc += h0 * at.x + h1 * at.y;
  }
#pragma unroll
  for (int off = 32; off > 0; off >>= 1) acc += __shfl_down(acc, off);
  if (lane == 0) {
    if (ACCUM) ev[edge] += acc;
    else ev[edge] = acc;
  }
}

template <typename TSL, typename TSR>
static void launch_edge_vec(const TSL* xl, int ldxl, const TSR* xr, int ldxr,
                            const int* cs, const int* cd,
                            const float* att, float* ev, int Etot, int Fc, bool accum,
                            hipStream_t st) {
  int blocks = (int)(((long long)Etot * 64 + 255) / 256);
  if (accum) edge_vec_kernel<TSL, TSR, true><<<blocks, 256, 0, st>>>(xl, ldxl, xr, ldxr, cs, cd, att, ev, Etot, Fc);
  else       edge_vec_kernel<TSL, TSR, false><<<blocks, 256, 0, st>>>(xl, ldxl, xr, ldxr, cs, cd, att, ev, Etot, Fc);
}

// ---------------- segment softmax ----------------

__global__ void softmax_kernel(float* __restrict__ ev, const int* __restrict__ indptr, int N) {
  int i = blockIdx.x * blockDim.x + threadIdx.x;
  if (i >= N) return;
  int lo = indptr[i], hi = indptr[i + 1];
  float m = -1e30f;
  for (int j = lo; j < hi; ++j) m = fmaxf(m, ev[j]);
  float s = 0.f;
  for (int j = lo; j < hi; ++j) { float x = expf(ev[j] - m); ev[j] = x; s += x; }
  float inv = 1.f / s;
  for (int j = lo; j < hi; ++j) ev[j] *= inv;
}

// ---------------- aggregation (vectorized; Fc = NP*128) ----------------

template <int NP, typename TS, typename TD>
__global__ void agg_vec_kernel(const TS* __restrict__ xl, int ldx,
                               const float* __restrict__ alpha,
                               const int* __restrict__ csr_src, const int* __restrict__ indptr,
                               const float* __restrict__ bias,
                               TD* __restrict__ out, int ldout, int N, int relu) {
  int gid = blockIdx.x * blockDim.x + threadIdx.x;
  int node = gid >> 6;
  int lane = threadIdx.x & 63;
  if (node >= N) return;
  float ax[NP], ay[NP];
#pragma unroll
  for (int p = 0; p < NP; ++p) {
    float2 b = *(const float2*)(bias + 2 * lane + p * 128);
    ax[p] = b.x; ay[p] = b.y;
  }
  int lo = indptr[node], hi = indptr[node + 1];
  for (int j = lo; j < hi; ++j) {
    float a = alpha[j];
    const TS* row = xl + (size_t)csr_src[j] * ldx;
#pragma unroll
    for (int p = 0; p < NP; ++p) {
      float2 v = ld2f(row + 2 * lane + p * 128);
      ax[p] += a * v.x;
      ay[p] += a * v.y;
    }
  }
#pragma unroll
  for (int p = 0; p < NP; ++p) {
    float vx = ax[p], vy = ay[p];
    if (relu) { vx = fmaxf(vx, 0.f); vy = fmaxf(vy, 0.f); }
    st2f(&out[(size_t)node * ldout + 2 * lane + p * 128], vx, vy);
  }
}

template <typename TS, typename TD>
static void launch_agg_vec(const TS* xl, int ldx, const float* alpha, const int* cs, const int* ip,
                           const float* bias, TD* out, int ldout, int N, int Fc, int relu,
                           hipStream_t st) {
  int blocks = (int)(((long long)N * 64 + 255) / 256);
  switch (Fc >> 7) {
    case 4: agg_vec_kernel<4, TS, TD><<<blocks, 256, 0, st>>>(xl, ldx, alpha, cs, ip, bias, out, ldout, N, relu); break;
    case 2: agg_vec_kernel<2, TS, TD><<<blocks, 256, 0, st>>>(xl, ldx, alpha, cs, ip, bias, out, ldout, N, relu); break;
    case 1: agg_vec_kernel<1, TS, TD><<<blocks, 256, 0, st>>>(xl, ldx, alpha, cs, ip, bias, out, ldout, N, relu); break;
  }
}

__global__ void aggregate3_kernel(const float* __restrict__ xl, const float* __restrict__ alpha,
                                  const int* __restrict__ csr_src, const int* __restrict__ indptr,
                                  const float* __restrict__ bias, float* __restrict__ out, int N) {
  int i = blockIdx.x * blockDim.x + threadIdx.x;
  if (i >= N) return;
  float a0 = bias[0], a1 = bias[1], a2 = bias[2];
  int lo = indptr[i], hi = indptr[i + 1];
  for (int j = lo; j < hi; ++j) {
    float a = alpha[j];
    const float* row = xl + (size_t)csr_src[j] * 3;
    a0 += a * row[0];
    a1 += a * row[1];
    a2 += a * row[2];
  }
  out[(size_t)i * 3 + 0] = a0;
  out[(size_t)i * 3 + 1] = a1;
  out[(size_t)i * 3 + 2] = a2;
}

// ---------------- launch ----------------

extern "C" void kernel_launch(void* const* d_in, const int* in_sizes, int n_in,
                              void* d_out, int out_size, void* d_ws, size_t ws_size,
                              hipStream_t stream) {
  const float* x = (const float*)d_in[0];
  const int* ei = (const int*)d_in[1];
  const int N = in_sizes[0] / 39;
  const int E = in_sizes[1] / 2;
  const int Etot = E + N;
  (void)n_in; (void)out_size;

  const float* Wl[5]; const float* Wr[5]; const float* att[5]; const float* bb[5];
  for (int l = 0; l < 5; ++l) {
    Wl[l]  = (const float*)d_in[2 + 4 * l];
    Wr[l]  = (const float*)d_in[3 + 4 * l];
    att[l] = (const float*)d_in[4 + 4 * l];
    bb[l]  = (const float*)d_in[5 + 4 * l];
  }

  char* ws = (char*)d_ws;
  size_t off = 0;
  auto alloc = [&](size_t b) -> char* {
    char* p = ws + off;
    off += (b + 255) & ~(size_t)255;
    return p;
  };
  int* counts  = (int*)alloc((size_t)N * 4);
  int* fillc   = (int*)alloc((size_t)N * 4);
  int* flag    = (int*)alloc(256);
  int* indptr  = (int*)alloc(((size_t)N + 1) * 4);
  int* csr_s   = (int*)alloc((size_t)Etot * 4);
  int* csr_d   = (int*)alloc((size_t)Etot * 4);
  float* ev    = (float*)alloc((size_t)Etot * 4);
  float* alpha1 = (float*)alloc((size_t)Etot * 4);
  size_t small_end = off;

  const size_t fat2_need = small_end + (size_t)N * (128 + 2048 + 1024) + 8192;
  const size_t slim_need = small_end + (size_t)N * (256 + 256 + 512 + 512 + 512) + 8192;
  if (ws_size < slim_need) return;

  const int tb = 256;
  init_counts_kernel<<<(N + tb - 1) / tb, tb, 0, stream>>>(counts, fillc, N, flag);
  detect_kernel<<<(E + tb - 1) / tb, tb, 0, stream>>>(ei, E, flag);
  count_kernel<<<(E + tb - 1) / tb, tb, 0, stream>>>(ei, E, flag, counts);
  scan_kernel<<<1, 256, 0, stream>>>(counts, indptr, N);
  fill_kernel<<<(Etot + tb - 1) / tb, tb, 0, stream>>>(ei, E, N, flag, indptr,
                                                       fillc, csr_s, csr_d);

  if (ws_size >= fat2_need) {
    // ============ FAT2: out1 + XL2 materialized, zero recompute ============
    bf16* xpad = (bf16*)alloc((size_t)N * 128);   // [N,64] bf16
    bf16* out1 = (bf16*)alloc((size_t)N * 2048);  // [N,1024] bf16; later out2/XL3/XR3
    bf16* XL2  = (bf16*)alloc((size_t)N * 1024);  // [N,512] bf16; later XL4/XR4/XL5/XR5
    bf16* xl1c = (bf16*)d_out;                    // d_out scratch (free until L4)
    bf16* xr1c = (bf16*)d_out + (size_t)N * 128;

    convert_pad_kernel<<<(N * 64 + tb - 1) / tb, tb, 0, stream>>>(x, xpad, N);

    // L1 scores
    for (int kc = 0; kc < 8; ++kc) {
      launch_mfma<true, bf16, bf16>(xpad, 64, N, 64, 39, Wl[0] + kc * 128, Wr[0] + kc * 128,
                                    1024, 128, xl1c, 128, xr1c, 128, false, stream);
      launch_edge_vec<bf16, bf16>(xl1c, 128, xr1c, 128, csr_s, csr_d, att[0] + kc * 128,
                                  ev, Etot, 128, kc > 0, stream);
    }
    softmax_kernel<<<(N + tb - 1) / tb, tb, 0, stream>>>(ev, indptr, N);
    // L1 materialize out1 (once)
    for (int kc = 0; kc < 8; ++kc) {
      launch_mfma<false, bf16, bf16>(xpad, 64, N, 64, 39, Wl[0] + kc * 128, Wl[0] + kc * 128,
                                     1024, 128, xl1c, 128, xl1c, 128, false, stream);
      launch_agg_vec<bf16, bf16>(xl1c, 128, ev, csr_s, indptr, bb[0] + kc * 128,
                                 out1 + kc * 128, 1024, N, 128, 1, stream);
    }

    // L2 scores: K=1024 dual GEMMs; XL2 stored, XR slice in d_out scratch
    for (int fc = 0; fc < 4; ++fc) {
      launch_mfma<true, bf16, bf16>(out1, 1024, N, 1024, 1024, Wl[1] + fc * 128, Wr[1] + fc * 128,
                                    512, 128, XL2 + fc * 128, 512, xl1c, 128, false, stream);
      launch_edge_vec<bf16, bf16>(XL2 + fc * 128, 512, xl1c, 128, csr_s, csr_d,
                                  att[1] + fc * 128, ev, Etot, 128, fc > 0, stream);
    }
    softmax_kernel<<<(N + tb - 1) / tb, tb, 0, stream>>>(ev, indptr, N);
    bf16* out2 = out1;  // out1 dead after L2 score GEMMs
    launch_agg_vec<bf16, bf16>(XL2, 512, ev, csr_s, indptr, bb[1], out2, 512, N, 512, 1, stream);

    // L3
    bf16* XL3 = out1 + (size_t)N * 512;
    bf16* XR3 = out1 + (size_t)N * 768;
    launch_mfma<true, bf16, bf16>(out2, 512, N, 512, 512, Wl[2], Wr[2], 256, 256,
                                  XL3, 256, XR3, 256, false, stream);
    launch_edge_vec<bf16, bf16>(XL3, 256, XR3, 256, csr_s, csr_d, att[2], ev, Etot, 256, false, stream);
    softmax_kernel<<<(N + tb - 1) / tb, tb, 0, stream>>>(ev, indptr, N);
    bf16* out3 = XR3;
    launch_agg_vec<bf16, bf16>(XL3, 256, ev, csr_s, indptr, bb[2], out3, 256, N, 256, 1, stream);

    // L4 -> d_out fp32
    bf16* XL4 = XL2;
    bf16* XR4 = XL2 + (size_t)N * 128;
    launch_mfma<true, bf16, bf16>(out3, 256, N, 256, 256, Wl[3], Wr[3], 128, 128,
                                  XL4, 128, XR4, 128, false, stream);
    launch_edge_vec<bf16, bf16>(XL4, 128, XR4, 128, csr_s, csr_d, att[3], ev, Etot, 128, false, stream);
    softmax_kernel<<<(N + tb - 1) / tb, tb, 0, stream>>>(ev, indptr, N);
    launch_agg_vec<bf16, float>(XL4, 128, ev, csr_s, indptr, bb[3], (float*)d_out, 128, N, 128, 1, stream);

    // L5
    float* XL5 = (float*)((char*)XL2 + (size_t)N * 512);
    float* XR5 = (float*)((char*)XL2 + (size_t)N * 512 + (((size_t)N * 12 + 255) & ~(size_t)255));
    launch_vgemm<float, float, float>((const float*)d_out, 128, N, 128, Wl[4], Wr[4], 3, 3,
                                      XL5, 3, XR5, 3, false, stream);
    launch_edge<float, float>(XL5, 3, XR5, 3, csr_s, csr_d, att[4], ev, Etot, 3, false, stream);
    softmax_kernel<<<(N + tb - 1) / tb, tb, 0, stream>>>(ev, indptr, N);
    aggregate3_kernel<<<(N + tb - 1) / tb, tb, 0, stream>>>(XL5, ev, csr_s, indptr, bb[4],
                                                            (float*)d_out + (size_t)N * 128, N);
    return;
  }

  // ============ SLIM-5: 5 recompute sweeps (d_out XL retention) ============
  char* R0 = alloc((size_t)N * 256);   // xl1c | XR3 low | out3 low
  char* R1 = alloc((size_t)N * 256);   // t1   | XR3 high | out3 high
  char* R2 = alloc((size_t)N * 512);   // waccL fp32 | XL3 | XL4+XR4
  char* R3 = alloc((size_t)N * 512);   // waccR fp32 | out2 low | XL5,XR5
  char* R4 = alloc((size_t)N * 512);   // out2 high
  (void)R4;
  size_t base_need = off + 4096;
  bool use_xpad = (ws_size >= base_need + (size_t)N * 128 + 256);
  bf16* xpad = use_xpad ? (bf16*)alloc((size_t)N * 128) : nullptr;

  bf16* xl1c = (bf16*)R0;
  bf16* t1   = (bf16*)R1;
  float* waccL = (float*)R2;
  float* waccR = (float*)R3;
  bf16* out2 = (bf16*)R3;              // spans R3+R4, [N,512] interleaved
  bf16* dXL1 = (bf16*)d_out;           // d_out scratch: XL2 slice fc=1 (bf16 [N,128])
  bf16* dXL2 = (bf16*)d_out + (size_t)N * 128;  // slice fc=2

  if (use_xpad)
    convert_pad_kernel<<<(N * 64 + tb - 1) / tb, tb, 0, stream>>>(x, xpad, N);

  // L1: alpha1 only; out1 virtual
  for (int kc = 0; kc < 8; ++kc) {
    if (use_xpad)
      launch_mfma<true, bf16, bf16>(xpad, 64, N, 64, 39, Wl[0] + kc * 128, Wr[0] + kc * 128,
                                    1024, 128, xl1c, 128, t1, 128, false, stream);
    else
      launch_vgemm<float, bf16, bf16>(x, 39, N, 39, Wl[0] + kc * 128, Wr[0] + kc * 128, 1024, 128,
                                      xl1c, 128, t1, 128, false, stream);
    launch_edge_vec<bf16, bf16>(xl1c, 128, t1, 128, csr_s, csr_d, att[0] + kc * 128,
                                ev, Etot, 128, kc > 0, stream);
  }
  softmax_kernel<<<(N + tb - 1) / tb, tb, 0, stream>>>(ev, indptr, N);
  copy_kernel<<<(Etot + tb - 1) / tb, tb, 0, stream>>>(ev, alpha1, Etot);

  auto mat_out1 = [&](int kc) {
    if (use_xpad)
      launch_mfma<false, bf16, bf16>(xpad, 64, N, 64, 39, Wl[0] + kc * 128, Wl[0] + kc * 128,
                                     1024, 128, xl1c, 128, xl1c, 128, false, stream);
    else
      launch_vgemm<float, bf16, bf16>(x, 39, N, 39, Wl[0] + kc * 128, nullptr, 1024, 128,
                                      xl1c, 128, xl1c, 128, false, stream);
    launch_agg_vec<bf16, bf16>(xl1c, 128, alpha1, csr_s, indptr, bb[0] + kc * 128,
                               t1, 128, N, 128, 1, stream);
  };

  // L2 score: 4 sweeps; retain XL slices (fc1,fc2 -> d_out bf16; fc3 stays in R2 fp32)
  for (int fc = 0; fc < 4; ++fc) {
    for (int kc = 0; kc < 8; ++kc) {
      mat_out1(kc);
      const float* wl = Wl[1] + (size_t)kc * 128 * 512 + fc * 128;
      const float* wr = Wr[1] + (size_t)kc * 128 * 512 + fc * 128;
      launch_mfma<true, float, float>(t1, 128, N, 128, 128, wl, wr, 512, 128,
                                      waccL, 128, waccR, 128, kc > 0, stream);
    }
    launch_edge_vec<float, float>(waccL, 128, waccR, 128, csr_s, csr_d,
                                  att[1] + fc * 128, ev, Etot, 128, fc > 0, stream);
    if (fc == 1)
      f2b_kernel<<<(N * 64 + tb - 1) / tb, tb, 0, stream>>>(waccL, dXL1, N * 64);
    if (fc == 2)
      f2b_kernel<<<(N * 64 + tb - 1) / tb, tb, 0, stream>>>(waccL, dXL2, N * 64);
  }
  softmax_kernel<<<(N + tb - 1) / tb, tb, 0, stream>>>(ev, indptr, N);

  // L2 out: aggs from retained slices; only fc0 recomputed (1 sweep)
  launch_agg_vec<float, bf16>(waccL, 128, ev, csr_s, indptr, bb[1] + 3 * 128,
                              out2 + 3 * 128, 512, N, 128, 1, stream);   // fc3 (fp32, R2)
  launch_agg_vec<bf16, bf16>(dXL1, 128, ev, csr_s, indptr, bb[1] + 1 * 128,
                             out2 + 1 * 128, 512, N, 128, 1, stream);    // fc1 (d_out)
  launch_agg_vec<bf16, bf16>(dXL2, 128, ev, csr_s, indptr, bb[1] + 2 * 128,
                             out2 + 2 * 128, 512, N, 128, 1, stream);    // fc2 (d_out)
  for (int kc = 0; kc < 8; ++kc) {                                       // fc0 sweep
    mat_out1(kc);
    const float* wl = Wl[1] + (size_t)kc * 128 * 512;
    launch_mfma<false, float, float>(t1, 128, N, 128, 128, wl, wl, 512, 128,
                                     waccL, 128, waccL, 128, kc > 0, stream);
  }
  launch_agg_vec<float, bf16>(waccL, 128, ev, csr_s, indptr, bb[1],
                              out2, 512, N, 128, 1, stream);             // fc0

  // L3
  bf16* XL3 = (bf16*)R2;
  bf16* XR3 = (bf16*)R0;  // spans R0+R1
  launch_mfma<true, bf16, bf16>(out2, 512, N, 512, 512, Wl[2], Wr[2], 256, 256,
                                XL3, 256, XR3, 256, false, stream);
  launch_edge_vec<bf16, bf16>(XL3, 256, XR3, 256, csr_s, csr_d, att[2], ev, Etot, 256, false, stream);
  softmax_kernel<<<(N + tb - 1) / tb, tb, 0, stream>>>(ev, indptr, N);
  bf16* out3 = XR3;
  launch_agg_vec<bf16, bf16>(XL3, 256, ev, csr_s, indptr, bb[2], out3, 256, N, 256, 1, stream);

  // L4 -> d_out fp32 (overwrites scratch slices, now dead)
  bf16* XL4 = (bf16*)R2;
  bf16* XR4 = (bf16*)(R2 + (size_t)N * 256);
  launch_mfma<true, bf16, bf16>(out3, 256, N, 256, 256, Wl[3], Wr[3], 128, 128,
                                XL4, 128, XR4, 128, false, stream);
  launch_edge_vec<bf16, bf16>(XL4, 128, XR4, 128, csr_s, csr_d, att[3], ev, Etot, 128, false, stream);
  softmax_kernel<<<(N + tb - 1) / tb, tb, 0, stream>>>(ev, indptr, N);
  launch_agg_vec<bf16, float>(XL4, 128, ev, csr_s, indptr, bb[3], (float*)d_out, 128, N, 128, 1, stream);

  // L5
  float* XL5 = (float*)R3;
  float* XR5 = (float*)(R3 + (((size_t)N * 12 + 255) & ~(size_t)255));
  launch_vgemm<float, float, float>((const float*)d_out, 128, N, 128, Wl[4], Wr[4], 3, 3,
                                    XL5, 3, XR5, 3, false, stream);
  launch_edge<float, float>(XL5, 3, XR5, 3, csr_s, csr_d, att[4], ev, Etot, 3, false, stream);
  softmax_kernel<<<(N + tb - 1) / tb, tb, 0, stream>>>(ev, indptr, N);
  aggregate3_kernel<<<(N + tb - 1) / tb, tb, 0, stream>>>(XL5, ev, csr_s, indptr, bb[4],
                                                          (float*)d_out + (size_t)N * 128, N);
}